// Round 10
// baseline (1747.507 us; speedup 1.0000x reference)
//
#include <hip/hip_runtime.h>
#include <math.h>

#define NB 8
#define NC 192
#define DIN 384
#define NL 3136
#define ROWS (NB*NL)     // 25088
#define NE 6160
#define NHID 768

typedef unsigned short u16;
typedef unsigned int u32;
typedef unsigned long long u64;
typedef __attribute__((ext_vector_type(8))) short bh8;
typedef __attribute__((ext_vector_type(4))) float f4;

// global_load_lds width=16: wave-uniform LDS base + lane*16; per-lane global src.
typedef __attribute__((address_space(1))) const void gl_as1;
typedef __attribute__((address_space(3))) void gl_as3;
#define GL16(g, l) __builtin_amdgcn_global_load_lds((gl_as1*)(const void*)(g), (gl_as3*)(void*)(l), 16, 0, 0)

// ---------- helpers ----------
__device__ __forceinline__ float wredsum(float v){
  v += __shfl_xor(v, 1, 64); v += __shfl_xor(v, 2, 64); v += __shfl_xor(v, 4, 64);
  v += __shfl_xor(v, 8, 64); v += __shfl_xor(v, 16, 64); v += __shfl_xor(v, 32, 64);
  return v;
}
__device__ __forceinline__ void edge_decode(int e, int& u, int& v){
  if (e < 3080){ int h = e/55, w = e - h*55; u = h*56 + w; v = u + 1; }
  else { int e2 = e - 3080; int h = e2/56, w = e2 - h*56; u = h*56 + w; v = u + 56; }
}
__device__ __forceinline__ float siluf(float x){ return x / (1.0f + expf(-x)); }
__device__ __forceinline__ float sofplus(float x){ return fmaxf(x, 0.0f) + log1pf(expf(-fabsf(x))); }
__device__ __forceinline__ float geluf(float x){ return 0.5f * x * (1.0f + erff(x * 0.70710678118654752f)); }
__device__ __forceinline__ u16 f2bf(float x){
  u32 u = __float_as_uint(x);
  u32 r = (u + 0x7fffu + ((u >> 16) & 1u)) >> 16;
  return (u16)r;
}
__device__ __forceinline__ float bf2f(u16 h){ return __uint_as_float(((u32)h) << 16); }

// ---------- node norms (wave per node) ----------
__global__ __launch_bounds__(256) void norms_kernel(const float* __restrict__ x, float* __restrict__ nrm){
  int gw = (int)((blockIdx.x * 256u + threadIdx.x) >> 6);
  int lane = threadIdx.x & 63;
  if (gw >= ROWS) return;
  const float* r = x + (size_t)gw * NC;
  float s = 0.f;
#pragma unroll
  for (int j = 0; j < 3; ++j){ float v = r[lane + 64*j]; s += v*v; }
  s = wredsum(s);
  if (lane == 0) nrm[gw] = sqrtf(s) + 1e-8f;
}

// ---------- edge keys (wave per edge) ----------
__global__ __launch_bounds__(256) void keys_kernel(const float* __restrict__ x, const float* __restrict__ nrm,
                                                   u64* __restrict__ keys){
  int gw = (int)((blockIdx.x * 256u + threadIdx.x) >> 6);
  int lane = threadIdx.x & 63;
  if (gw >= NB * NE) return;
  int b = gw / NE, e = gw - b * NE;
  int u, v; edge_decode(e, u, v);
  const float* ru = x + ((size_t)b * NL + u) * NC;
  const float* rv = x + ((size_t)b * NL + v) * NC;
  float s = 0.f;
#pragma unroll
  for (int j = 0; j < 3; ++j){ s += ru[lane + 64*j] * rv[lane + 64*j]; }
  s = wredsum(s);
  if (lane == 0){
    float cosv = s / (nrm[b*NL + u] * nrm[b*NL + v]);
    float wgt = expf(1.0f - cosv);
    keys[(size_t)b*NE + e] = ((u64)__float_as_uint(wgt) << 32) | (u64)(u32)e;
  }
}

// ---------- per-image: Boruvka MST + CSR + BFS levels ----------
__global__ __launch_bounds__(1024) void tree_kernel(const u64* __restrict__ keys_g,
      int* __restrict__ order_g, int* __restrict__ parpos_g, int* __restrict__ pos_g,
      int* __restrict__ lvl_g, int* __restrict__ nlev_g){
  __shared__ __align__(16) char sm[62736];
  const int b = blockIdx.x;
  const int t = threadIdx.x;
  const int NT = 1024;
  u64* best   = (u64*)sm;            // [3136]  (phase B)
  u16* parent = (u16*)(sm + 25088);
  u16* comp   = (u16*)(sm + 31360);
  u16* mstU   = (u16*)(sm + 37632);
  u16* mstV   = (u16*)(sm + 43904);
  u16* adjl   = (u16*)(sm + 50176);  // [6270]
  u32* cnts   = (u32*)(sm + 62720);  // [4]
  u32* deg    = (u32*)sm;            // [3136]
  u32* offA   = (u32*)(sm + 12544);  // [3137]
  u32* aux    = (u32*)(sm + 25096);  // [1024]
  u16* bfs    = (u16*)sm;            // [3136] (phase D)
  u16* ppos   = (u16*)(sm + 6272);   // [3136]
  u16* posOf  = (u16*)(sm + 29192);  // [3136]

  const u64* kb = keys_g + (size_t)b * NE;
  for (int v = t; v < NL; v += NT) parent[v] = (u16)v;
  if (t == 0){ cnts[0] = 0; cnts[3] = 0xffffffffu; }
  __syncthreads();

  u32 gpass = 0;
  for (int round = 0; round < 24; ++round){
    for (int it = 0; it < 12; ++it){
      bool ch = false;
      for (int v = t; v < NL; v += NT){
        u16 pv = parent[v]; u16 gpv = parent[pv];
        if (gpv != pv){ parent[v] = gpv; ch = true; }
      }
      if (ch) cnts[3] = gpass;
      __syncthreads();
      u32 seen = cnts[3];
      __syncthreads();
      u32 cur = gpass; ++gpass;
      if (seen != cur) break;
    }
    for (int v = t; v < NL; v += NT){ comp[v] = parent[v]; best[v] = ~0ull; }
    if (t == 0) cnts[2] = 0;
    __syncthreads();
    for (int e = t; e < NE; e += NT){
      int u, v; edge_decode(e, u, v);
      u16 ru = comp[u], rv = comp[v];
      if (ru != rv){
        u64 k = kb[e];
        atomicMin(&best[ru], k);
        atomicMin(&best[rv], k);
      }
    }
    __syncthreads();
    for (int r = t; r < NL; r += NT){
      if (comp[r] == (u16)r){
        u64 bk = best[r];
        if (bk != ~0ull){
          int e = (int)(u32)bk; int u, v; edge_decode(e, u, v);
          u16 ru = comp[u], rv = comp[v];
          u16 other = (ru == (u16)r) ? rv : ru;
          bool mutual = (best[other] == bk);
          if (!mutual || (u16)r < other){
            parent[r] = other;
            u32 id = atomicAdd(&cnts[0], 1);
            mstU[id] = (u16)u; mstV[id] = (u16)v;
            cnts[2] = 1;
          }
        }
      }
    }
    __syncthreads();
    if (cnts[0] >= (u32)(NL - 1) || cnts[2] == 0) break;
  }
  __syncthreads();

  const int nm = NL - 1;
  for (int v = t; v < NL; v += NT) deg[v] = 0;
  __syncthreads();
  for (int i = t; i < nm; i += NT){ atomicAdd(&deg[mstU[i]], 1); atomicAdd(&deg[mstV[i]], 1); }
  __syncthreads();
  u32 loc[4]; u32 s = 0;
#pragma unroll
  for (int j = 0; j < 4; ++j){ int v = t*4 + j; u32 d = (v < NL) ? deg[v] : 0; loc[j] = s; s += d; }
  aux[t] = s; __syncthreads();
  for (int st = 1; st < 1024; st <<= 1){
    u32 mine = aux[t]; u32 add = (t >= st) ? aux[t - st] : 0; __syncthreads();
    aux[t] = mine + add; __syncthreads();
  }
  u32 base = (t > 0) ? aux[t-1] : 0;
#pragma unroll
  for (int j = 0; j < 4; ++j){ int v = t*4 + j; if (v < NL) offA[v] = base + loc[j]; }
  if (t == 0) offA[NL] = aux[1023];
  __syncthreads();
  for (int v = t; v < NL; v += NT) deg[v] = offA[v];
  __syncthreads();
  for (int i = t; i < nm; i += NT){
    int u = mstU[i], v = mstV[i];
    u32 p1 = atomicAdd(&deg[u], 1); adjl[p1] = (u16)v;
    u32 p2 = atomicAdd(&deg[v], 1); adjl[p2] = (u16)u;
  }
  __syncthreads();

  for (int v = t; v < NL; v += NT) posOf[v] = 0xffffu;
  __syncthreads();
  if (t == 0){
    bfs[0] = 0; ppos[0] = 0; posOf[0] = 0; cnts[1] = 1;
    lvl_g[b*3200 + 0] = 0; lvl_g[b*3200 + 1] = 1;
  }
  __syncthreads();
  int flo = 0, fhi = 1, d = 1;
  while (fhi < NL){
    for (int idx = flo + t; idx < fhi; idx += NT){
      int u = bfs[idx];
      int k0 = offA[u], k1 = offA[u + 1];
      for (int k = k0; k < k1; ++k){
        int v = adjl[k];
        if (posOf[v] == 0xffffu){
          u32 pos = atomicAdd(&cnts[1], 1);
          bfs[pos] = (u16)v; ppos[pos] = (u16)idx; posOf[v] = (u16)pos;
        }
      }
    }
    __syncthreads();
    int nf = (int)cnts[1];
    if (t == 0) lvl_g[b*3200 + d + 1] = nf;
    flo = fhi; fhi = nf; ++d;
    __syncthreads();
    if (nf == flo) break;
  }
  if (t == 0) nlev_g[b] = d;
  for (int p = t; p < NL; p += NT){
    order_g[b*NL + p] = (int)bfs[p];
    parpos_g[b*NL + p] = (int)ppos[p];
    pos_g[b*NL + p] = (int)posOf[p];
  }
}

// ---------- layernorm (wave per row); SPLIT -> bf16 hi|lo pair output ----------
template<int D, bool SPLIT>
__global__ __launch_bounds__(256) void ln_kernel(const float* __restrict__ in, const float* __restrict__ g,
                                                 const float* __restrict__ bt, void* __restrict__ outv){
  int gw = (int)((blockIdx.x * 256u + threadIdx.x) >> 6);
  int lane = threadIdx.x & 63;
  if (gw >= ROWS) return;
  constexpr int J = D / 64;
  const float* r = in + (size_t)gw * D;
  float v[J]; float s = 0.f;
#pragma unroll
  for (int j = 0; j < J; ++j){ v[j] = r[lane + 64*j]; s += v[j]; }
  s = wredsum(s);
  float mu = s * (1.0f / D);
  float q = 0.f;
#pragma unroll
  for (int j = 0; j < J; ++j){ float dd = v[j] - mu; q += dd*dd; }
  q = wredsum(q);
  float rs = rsqrtf(q * (1.0f / D) + 1e-5f);
  if (SPLIT){
    u16* o = (u16*)outv + (size_t)gw * (2*D);
#pragma unroll
    for (int j = 0; j < J; ++j){
      int dch = lane + 64*j;
      float y = (v[j] - mu) * rs * g[dch] + bt[dch];
      u16 hi = f2bf(y);
      o[dch] = hi; o[D + dch] = f2bf(y - bf2f(hi));
    }
  } else {
    float* o = (float*)outv + (size_t)gw * D;
#pragma unroll
    for (int j = 0; j < J; ++j){ int dch = lane + 64*j; o[dch] = (v[j] - mu) * rs * g[dch] + bt[dch]; }
  }
}

// ---------- weight split fp32 [N,K] -> bf16 [N, hi(K)|lo(K)] ----------
__global__ __launch_bounds__(256) void wsplit_kernel(const float* __restrict__ W, u16* __restrict__ o, int N, int K){
  int i = blockIdx.x * 256 + threadIdx.x;
  if (i >= N * K) return;
  int r = i / K, c = i - r * K;
  float v = W[i];
  u16 hi = f2bf(v);
  o[(size_t)r * 2 * K + c] = hi;
  o[(size_t)r * 2 * K + K + c] = f2bf(v - bf2f(hi));
}

// ---------- MFMA GEMM via hi/lo split; global_load_lds staging (pre-swizzled src).
// DUALOUT: N=768, cols<384 -> Cm (stride 384), cols>=384 -> C2 (stride 384). ----------
template<int BN, bool BIAS, int ACT, bool RESID, bool OSPLIT, bool DUALOUT>
__global__ __launch_bounds__(256) void mgemm_kernel(
    const u16* __restrict__ Ap, const u16* __restrict__ Wp,
    const float* __restrict__ bias, const float* __restrict__ resid,
    float* __restrict__ Cm, float* __restrict__ C2, int M, int N, int K){
  static_assert(BN == 64 || BN == 128, "BN");
  constexpr int WT = (BN == 128) ? 64 : 32;
  constexpr int NF = WT / 16;
  __shared__ short Ah[128*64], Al[128*64];
  __shared__ short Wh[BN*64], Wl[BN*64];
  const int bm = blockIdx.y * 128, bn = blockIdx.x * BN;
  const int tid = threadIdx.x, lane = tid & 63, wid = tid >> 6;
  const int wr = wid >> 1, wc = wid & 1;
  const int K2 = 2 * K;
  f4 acc[4][NF];
#pragma unroll
  for (int mf = 0; mf < 4; ++mf)
#pragma unroll
    for (int nf = 0; nf < NF; ++nf) acc[mf][nf] = (f4){0.f,0.f,0.f,0.f};

  for (int k0 = 0; k0 < K; k0 += 64){
#pragma unroll
    for (int j = 0; j < 4; ++j){
      int isb = wid*4 + j;
      int r = isb*8 + (lane >> 3);
      int c = lane & 7;
      const u16* src = Ap + (size_t)(bm + r) * K2 + k0 + ((c ^ (r & 7)) << 3);
      GL16(src,     &Ah[isb*512]);
      GL16(src + K, &Al[isb*512]);
    }
#pragma unroll
    for (int j = 0; j < BN/32; ++j){
      int isb = wid*(BN/32) + j;
      int r = isb*8 + (lane >> 3);
      int c = lane & 7;
      const u16* src = Wp + (size_t)(bn + r) * K2 + k0 + ((c ^ (r & 7)) << 3);
      GL16(src,     &Wh[isb*512]);
      GL16(src + K, &Wl[isb*512]);
    }
    __syncthreads();
#pragma unroll
    for (int kk = 0; kk < 2; ++kk){
      bh8 whf[NF], wlf[NF], ahf[4], alf[4];
#pragma unroll
      for (int nf = 0; nf < NF; ++nf){
        int rw = wc*WT + nf*16 + (lane & 15);
        int c = kk*4 + (lane >> 4);
        int ad = rw*64 + ((c ^ (rw & 7)) * 8);
        whf[nf] = *(const bh8*)&Wh[ad];
        wlf[nf] = *(const bh8*)&Wl[ad];
      }
#pragma unroll
      for (int mf = 0; mf < 4; ++mf){
        int ra = wr*64 + mf*16 + (lane & 15);
        int c = kk*4 + (lane >> 4);
        int ad = ra*64 + ((c ^ (ra & 7)) * 8);
        ahf[mf] = *(const bh8*)&Ah[ad];
        alf[mf] = *(const bh8*)&Al[ad];
      }
#pragma unroll
      for (int mf = 0; mf < 4; ++mf)
#pragma unroll
        for (int nf = 0; nf < NF; ++nf){
          acc[mf][nf] = __builtin_amdgcn_mfma_f32_16x16x32_bf16(ahf[mf], whf[nf], acc[mf][nf], 0, 0, 0);
          acc[mf][nf] = __builtin_amdgcn_mfma_f32_16x16x32_bf16(ahf[mf], wlf[nf], acc[mf][nf], 0, 0, 0);
          acc[mf][nf] = __builtin_amdgcn_mfma_f32_16x16x32_bf16(alf[mf], whf[nf], acc[mf][nf], 0, 0, 0);
        }
    }
    __syncthreads();
  }
  const int cb = bn + wc*WT;
#pragma unroll
  for (int mf = 0; mf < 4; ++mf){
    int row = bm + wr*64 + mf*16 + (lane >> 4)*4;
#pragma unroll
    for (int nf = 0; nf < NF; ++nf){
      int col = cb + nf*16 + (lane & 15);
#pragma unroll
      for (int r = 0; r < 4; ++r){
        float v = acc[mf][nf][r];
        if (BIAS) v += bias[col];
        if (ACT == 1) v = geluf(v);
        if (RESID) v += resid[(size_t)(row + r) * N + col];
        if (DUALOUT){
          float* op = (col < 384) ? Cm : C2;
          int oc = (col < 384) ? col : col - 384;
          op[(size_t)(row + r) * 384 + oc] = v;
        } else if (OSPLIT){
          u16* Gp = (u16*)Cm;
          u16 hi = f2bf(v);
          Gp[(size_t)(row + r) * (2*N) + col] = hi;
          Gp[(size_t)(row + r) * (2*N) + N + col] = f2bf(v - bf2f(hi));
        } else {
          Cm[(size_t)(row + r) * N + col] = v;
        }
      }
    }
  }
}

// ---------- depthwise conv 3x3 SAME + bias + silu ----------
__global__ __launch_bounds__(256) void conv_kernel(const float* __restrict__ xs, const float* __restrict__ cw,
                                                   const float* __restrict__ cb, float* __restrict__ u){
  int idx = blockIdx.x * 256 + threadIdx.x;
  if (idx >= ROWS * 96) return;
  int q = idx % 96; int l = idx / 96;
  int b = l / NL; int hw = l - b * NL; int h = hw / 56; int wc = hw - h * 56;
  int c4 = q * 4;
  float4 acc = *(const float4*)(cb + c4);
#pragma unroll
  for (int kh = 0; kh < 3; ++kh){
    int hh = h + kh - 1; if (hh < 0 || hh >= 56) continue;
#pragma unroll
    for (int kw = 0; kw < 3; ++kw){
      int wwc = wc + kw - 1; if (wwc < 0 || wwc >= 56) continue;
      float4 iv = *(const float4*)(xs + ((size_t)(b * NL + hh*56 + wwc)) * DIN + c4);
      float4 wv = *(const float4*)(cw + (size_t)(kh*3 + kw) * DIN + c4);
      acc.x += iv.x * wv.x; acc.y += iv.y * wv.y; acc.z += iv.z * wv.z; acc.w += iv.w * wv.w;
    }
  }
  float4 o; o.x = siluf(acc.x); o.y = siluf(acc.y); o.z = siluf(acc.z); o.w = siluf(acc.w);
  *(float4*)(u + (size_t)l * DIN + c4) = o;
}

// ---------- x_proj + dt_proj + softplus + w/feat (wave per row), BFS-pos output ----------
__global__ __launch_bounds__(256) void xdbl_kernel(const float* __restrict__ u,
    const float* __restrict__ xpw, const float* __restrict__ dtw_g,
    const float* __restrict__ dtb, const float* __restrict__ alog, const int* __restrict__ pos_g,
    float* __restrict__ wout, float* __restrict__ fout, float* __restrict__ csout){
  __shared__ float xw[14*384];
  __shared__ float dw[384*12];
  __shared__ float db[384];
  __shared__ float An[384];
  int t = threadIdx.x;
  for (int i = t; i < 14*384; i += 256) xw[i] = xpw[i];
  for (int i = t; i < 384*12; i += 256) dw[i] = dtw_g[i];
  for (int i = t; i < 384; i += 256){ db[i] = dtb[i]; An[i] = -expf(alog[i]); }
  __syncthreads();
  int wave = t >> 6, lane = t & 63;
  int row0 = blockIdx.x * 16 + wave * 4;
  for (int rr = 0; rr < 4; ++rr){
    int m = row0 + rr;
    int b = m / NL;
    int pos = pos_g[m];
    size_t orow = ((size_t)b * NL + pos) * DIN;
    const float* ur = u + (size_t)m * DIN;
    float u6[6];
#pragma unroll
    for (int j = 0; j < 6; ++j) u6[j] = ur[lane + 64*j];
    float xd[14];
#pragma unroll
    for (int r = 0; r < 14; ++r){
      float p = 0.f;
#pragma unroll
      for (int j = 0; j < 6; ++j) p += u6[j] * xw[r*384 + lane + 64*j];
      xd[r] = wredsum(p);
    }
    float Bs = xd[12], Cv = xd[13];
#pragma unroll
    for (int j = 0; j < 6; ++j){
      int dch = lane + 64*j;
      float pre = db[dch];
#pragma unroll
      for (int r = 0; r < 12; ++r) pre += xd[r] * dw[dch*12 + r];
      float dts = sofplus(pre);
      float wv = expf(dts * An[dch]);
      float fv = dts * Bs * u6[j];
      wout[orow + dch] = wv;
      fout[orow + dch] = fv;
    }
    if (lane == 0) csout[m] = Cv;
  }
}

// ---------- w transpose: [b][pos][384] -> planar [b][ch][pos] (64x64 LDS tiles) ----------
__global__ __launch_bounds__(256) void wtr_kernel(const float* __restrict__ in, float* __restrict__ out){
  __shared__ float tile[64][65];
  int blk = blockIdx.x;                  // 8 * 49 * 6
  int b = blk / (49*6);
  int r = blk - b*(49*6);
  int pt = r / 6, ct = r - pt*6;         // pos tile, channel tile
  int t = threadIdx.x;
  int tr = t >> 6, lane = t & 63;
  const float* src = in + ((size_t)b*NL + (size_t)pt*64) * DIN + ct*64;
#pragma unroll
  for (int k = 0; k < 16; ++k){
    int rr = tr + k*4;
    tile[rr][lane] = src[(size_t)rr*DIN + lane];
  }
  __syncthreads();
  float* dst = out + ((size_t)b*DIN + (size_t)ct*64) * NL + (size_t)pt*64;
#pragma unroll
  for (int k = 0; k < 16; ++k){
    int cc = tr + k*4;
    dst[(size_t)cc*NL + lane] = tile[lane][cc];
  }
}

// ---------- tree sweep v7: planar channel planes + PLANAR w stream (contiguous
// 256B window loads). One wave per channel, zero inter-wave barriers. ----------
__global__ __launch_bounds__(256) void sweep7_kernel(const float* __restrict__ featp, const float* __restrict__ wtr,
    float* __restrict__ Hp, const int* __restrict__ parpos_g,
    const int* __restrict__ lvl_g, const int* __restrict__ nlev_g){
  __shared__ float S[4*NL];    // 4 planar channel planes, 50176B -> 3 blocks/CU
  int blk = blockIdx.x;
  int b = blk & 7, q = blk >> 3;   // tree b pinned to XCD b
  int t = threadIdx.x, lane = t & 63, wv = t >> 6;
  int nl = nlev_g[b];
  const int* pg = parpos_g + b*NL;
  const int* lg = lvl_g + b*3200;
  const float* fbase = featp + (size_t)b*NL*DIN + q*4;
  const float* wbase = wtr + ((size_t)b*DIN + q*4 + wv) * NL;   // planar: this wave's channel row
  float*       hbase = Hp    + (size_t)b*NL*DIN + q*4;
  for (int i = t; i < NL; i += 256){
    float4 f = *(const float4*)(fbase + (size_t)i*DIN);
    S[0*NL + i] = f.x; S[1*NL + i] = f.y; S[2*NL + i] = f.z; S[3*NL + i] = f.w;
  }
  __syncthreads();
  float* Sp = &S[wv*NL];   // this wave's plane; no other wave touches it

  // ---- up-sweep: levels nl-1 .. 1, 64-wide windows, no barriers ----
  if (nl >= 2){
    int d  = nl - 1;
    int lo = lg[d], hi = lg[d+1];
    int nlo = (d >= 2) ? lg[d-1] : 0;
    float wc = 0.f; int ppc = 0;
    { int p = lo + lane; if (p < hi){ wc = wbase[p]; ppc = pg[p]; } }
    int base = lo;
    while (1){
      int d2 = d, nb = base + 64, nhi = hi, nlo2 = nlo, lo2 = lo;
      bool lvlchange = false;
      if (nb >= hi){
        d2 = d - 1; lvlchange = true;
        if (d2 >= 1){
          nb = nlo; nhi = lo; lo2 = nlo;
          nlo2 = (d2 >= 2) ? lg[d2-1] : 0;
        }
      }
      float wn = 0.f; int ppn = 0;
      if (d2 >= 1){ int pn = nb + lane; if (pn < nhi){ wn = wbase[pn]; ppn = pg[pn]; } }
      int p = base + lane;
      if (p < hi){
        float s = Sp[p];
        atomicAdd(&Sp[ppc], wc * s);
      }
      if (lvlchange){
        asm volatile("s_waitcnt lgkmcnt(0)" ::: "memory");   // intra-wave LDS ordering only
      }
      if (d2 < 1) break;
      d = d2; base = nb; hi = nhi; lo = lo2; nlo = nlo2; wc = wn; ppc = ppn;
    }
  }

  // ---- down-sweep: levels 1 .. nl-1 ----
  if (nl >= 2){
    int d = 1;
    int lo = lg[1], hi = lg[2];
    int hi2 = (nl >= 3) ? lg[3] : 0;
    float wc = 0.f; int ppc = 0;
    { int p = lo + lane; if (p < hi){ wc = wbase[p]; ppc = pg[p]; } }
    int base = lo;
    while (1){
      int d2 = d, nb = base + 64, nhi = hi, hi2n = hi2;
      bool lvlchange = false;
      if (nb >= hi){
        d2 = d + 1; lvlchange = true;
        nb = hi; nhi = hi2;
        hi2n = (d2 + 2 <= nl) ? lg[d2+2] : 0;
      }
      float wn = 0.f; int ppn = 0;
      if (d2 <= nl-1){ int pn = nb + lane; if (pn < nhi){ wn = wbase[pn]; ppn = pg[pn]; } }
      int p = base + lane;
      if (p < hi){
        float s = Sp[p]; float h = Sp[ppc];
        Sp[p] = s + wc * (h - wc * s);
      }
      if (lvlchange){
        asm volatile("s_waitcnt lgkmcnt(0)" ::: "memory");
      }
      if (d2 > nl-1) break;
      d = d2; base = nb; hi = nhi; hi2 = hi2n; wc = wn; ppc = ppn;
    }
  }

  __syncthreads();
  for (int i = t; i < NL; i += 256){
    float4 o;
    o.x = S[0*NL + i]; o.y = S[1*NL + i]; o.z = S[2*NL + i]; o.w = S[3*NL + i];
    *(float4*)(hbase + (size_t)i*DIN) = o;
  }
}

// ---------- y = Cs*H + Ds*u -> LN -> * silu(z) -> bf16 hi|lo pair (pos-row input) ----------
__global__ __launch_bounds__(256) void ynorm_kernel(const float* __restrict__ Hp, const float* __restrict__ u,
    const float* __restrict__ z, const float* __restrict__ Cs, const int* __restrict__ order_g,
    const float* __restrict__ Ds, const float* __restrict__ g, const float* __restrict__ bt,
    u16* __restrict__ out){
  int gw = (int)((blockIdx.x * 256u + threadIdx.x) >> 6);   // pos-row
  int lane = threadIdx.x & 63;
  if (gw >= ROWS) return;
  int b = gw / NL;
  int node = order_g[gw];
  size_t nrow = (size_t)b * NL + node;
  float Cv = Cs[nrow];
  const float* hr = Hp + (size_t)gw * DIN;
  const float* ur = u + nrow * DIN;
  const float* zr = z + nrow * DIN;
  float y[6]; float s = 0.f;
#pragma unroll
  for (int j = 0; j < 6; ++j){
    int dch = lane + 64*j;
    y[j] = Cv * hr[dch] + Ds[dch] * ur[dch];
    s += y[j];
  }
  s = wredsum(s);
  float mu = s * (1.0f / DIN);
  float q = 0.f;
#pragma unroll
  for (int j = 0; j < 6; ++j){ float dd = y[j] - mu; q += dd*dd; }
  q = wredsum(q);
  float rs = rsqrtf(q * (1.0f / DIN) + 1e-5f);
  u16* o = out + nrow * (2*DIN);
#pragma unroll
  for (int j = 0; j < 6; ++j){
    int dch = lane + 64*j;
    float yn = (y[j] - mu) * rs * g[dch] + bt[dch];
    float v = yn * siluf(zr[dch]);
    u16 hi = f2bf(v);
    o[dch] = hi; o[DIN + dch] = f2bf(v - bf2f(hi));
  }
}

// ---------- host orchestration ----------
extern "C" void kernel_launch(void* const* d_in, const int* in_sizes, int n_in,
                              void* d_out, int out_size, void* d_ws, size_t ws_size,
                              hipStream_t stream){
  const float* x_in       = (const float*)d_in[0];
  const float* norm1_w    = (const float*)d_in[1];
  const float* norm1_b    = (const float*)d_in[2];
  const float* in_proj_w  = (const float*)d_in[3];
  const float* conv_w     = (const float*)d_in[4];
  const float* conv_b     = (const float*)d_in[5];
  const float* x_proj_w   = (const float*)d_in[6];
  const float* dt_proj_w  = (const float*)d_in[7];
  const float* dt_proj_b  = (const float*)d_in[8];
  const float* A_log      = (const float*)d_in[9];
  const float* Ds         = (const float*)d_in[10];
  const float* out_norm_w = (const float*)d_in[11];
  const float* out_norm_b = (const float*)d_in[12];
  const float* out_proj_w = (const float*)d_in[13];
  const float* norm2_w    = (const float*)d_in[14];
  const float* norm2_b    = (const float*)d_in[15];
  const float* fc1_w      = (const float*)d_in[16];
  const float* fc1_b      = (const float*)d_in[17];
  const float* fc2_w      = (const float*)d_in[18];
  const float* fc2_b      = (const float*)d_in[19];
  const float* fnorm_w    = (const float*)d_in[20];
  const float* fnorm_b    = (const float*)d_in[21];

  float* ws = (float*)d_ws;
  float* X     = ws + 0;
  u16*   bufAh = (u16*)(ws + 4816896);
  float* bufZ  = ws + 9633792;
  float* bufW  = ws + 19267584;
  float* bufU  = ws + 28901376;
  float* bufF  = ws + 38535168;
  u16*   Gp    = (u16*)bufU;
  float* Csb   = ws + 48168960;
  int*   ordg  = (int*)(ws + 48194048);
  int*   ppg   = (int*)(ws + 48219136);
  int*   lvlg  = (int*)(ws + 48244224);
  int*   nlvg  = (int*)(ws + 48269824);
  u64*   keysg = (u64*)(ws + 48269832);
  float* nrm   = ws + 48368392;
  u16*   ipWp  = (u16*)(ws + 48393480);
  u16*   opWp  = (u16*)(ws + 48540936);
  u16*   fc1Wp = (u16*)(ws + 48614664);
  u16*   fc2Wp = (u16*)(ws + 48762120);
  int*   posg  = (int*)(ws + 48909576);
  float* wtrp  = ws + 48934664;          // planar w [b][384][NL], 9633792 f

  hipMemcpyAsync(X, x_in, (size_t)ROWS * NC * sizeof(float), hipMemcpyDeviceToDevice, stream);

  for (int i = 0; i < 2; ++i){
    wsplit_kernel<<<(768*192+255)/256, 256, 0, stream>>>(in_proj_w + (size_t)i*NHID*NC, ipWp, 768, 192);
    wsplit_kernel<<<(192*384+255)/256, 256, 0, stream>>>(out_proj_w + (size_t)i*NC*DIN, opWp, 192, 384);
    wsplit_kernel<<<(768*192+255)/256, 256, 0, stream>>>(fc1_w + (size_t)i*NHID*NC, fc1Wp, 768, 192);
    wsplit_kernel<<<(192*768+255)/256, 256, 0, stream>>>(fc2_w + (size_t)i*NC*NHID, fc2Wp, 192, 768);

    norms_kernel<<<ROWS/4, 256, 0, stream>>>(X, nrm);
    keys_kernel<<<(NB*NE)/4, 256, 0, stream>>>(X, nrm, keysg);
    tree_kernel<<<NB, 1024, 0, stream>>>(keysg, ordg, ppg, posg, lvlg, nlvg);

    ln_kernel<192,true><<<ROWS/4, 256, 0, stream>>>(X, norm1_w + i*NC, norm1_b + i*NC, bufAh);
    // fused in_proj: N=768, xs half -> bufF, z half -> bufZ
    mgemm_kernel<128,false,0,false,false,true><<<dim3(6,196), 256, 0, stream>>>(bufAh, ipWp, nullptr, nullptr, bufF, bufZ, ROWS, 768, 192);

    conv_kernel<<<(ROWS*96)/256, 256, 0, stream>>>(bufF, conv_w + (size_t)i*9*DIN, conv_b + i*DIN, bufU);

    // w/feat written in BFS-pos order (bufW = wperm, bufF = featperm)
    xdbl_kernel<<<ROWS/16, 256, 0, stream>>>(bufU, x_proj_w + (size_t)i*14*DIN, dt_proj_w + (size_t)i*DIN*12,
                                             dt_proj_b + i*DIN, A_log + i*DIN, posg, bufW, bufF, Csb);

    // transpose w to planar [b][ch][pos]
    wtr_kernel<<<8*49*6, 256, 0, stream>>>(bufW, wtrp);

    sweep7_kernel<<<NB*96, 256, 0, stream>>>(bufF, wtrp, bufF, ppg, lvlg, nlvg);

    ynorm_kernel<<<ROWS/4, 256, 0, stream>>>(bufF, bufU, bufZ, Csb, ordg, Ds + i*DIN,
                                             out_norm_w + i*DIN, out_norm_b + i*DIN, (u16*)bufW);

    mgemm_kernel<64,false,0,true,false,false><<<dim3(3,196), 256, 0, stream>>>((u16*)bufW, opWp, nullptr, X, X, nullptr, ROWS, 192, 384);

    ln_kernel<192,true><<<ROWS/4, 256, 0, stream>>>(X, norm2_w + i*NC, norm2_b + i*NC, bufAh);
    mgemm_kernel<128,true,1,false,true,false><<<dim3(6,196), 256, 0, stream>>>(bufAh, fc1Wp, fc1_b + i*NHID, nullptr, (float*)Gp, nullptr, ROWS, NHID, 192);
    mgemm_kernel<64,true,0,true,false,false><<<dim3(3,196), 256, 0, stream>>>(Gp, fc2Wp, fc2_b + i*NC, X, X, nullptr, ROWS, 192, 768);
  }

  ln_kernel<192,false><<<ROWS/4, 256, 0, stream>>>(X, fnorm_w, fnorm_b, d_out);
}

// Round 11
// 1726.428 us; speedup vs baseline: 1.0122x; 1.0122x over previous
//
#include <hip/hip_runtime.h>
#include <math.h>

#define NB 8
#define NC 192
#define DIN 384
#define NL 3136
#define ROWS (NB*NL)     // 25088
#define NE 6160
#define NHID 768

typedef unsigned short u16;
typedef unsigned int u32;
typedef unsigned long long u64;
typedef __attribute__((ext_vector_type(8))) short bh8;
typedef __attribute__((ext_vector_type(4))) float f4;

// global_load_lds width=16: wave-uniform LDS base + lane*16; per-lane global src.
typedef __attribute__((address_space(1))) const void gl_as1;
typedef __attribute__((address_space(3))) void gl_as3;
#define GL16(g, l) __builtin_amdgcn_global_load_lds((gl_as1*)(const void*)(g), (gl_as3*)(void*)(l), 16, 0, 0)

// ---------- helpers ----------
__device__ __forceinline__ float wredsum(float v){
  v += __shfl_xor(v, 1, 64); v += __shfl_xor(v, 2, 64); v += __shfl_xor(v, 4, 64);
  v += __shfl_xor(v, 8, 64); v += __shfl_xor(v, 16, 64); v += __shfl_xor(v, 32, 64);
  return v;
}
__device__ __forceinline__ void edge_decode(int e, int& u, int& v){
  if (e < 3080){ int h = e/55, w = e - h*55; u = h*56 + w; v = u + 1; }
  else { int e2 = e - 3080; int h = e2/56, w = e2 - h*56; u = h*56 + w; v = u + 56; }
}
__device__ __forceinline__ float siluf(float x){ return x / (1.0f + expf(-x)); }
__device__ __forceinline__ float sofplus(float x){ return fmaxf(x, 0.0f) + log1pf(expf(-fabsf(x))); }
__device__ __forceinline__ float geluf(float x){ return 0.5f * x * (1.0f + erff(x * 0.70710678118654752f)); }
__device__ __forceinline__ u16 f2bf(float x){
  u32 u = __float_as_uint(x);
  u32 r = (u + 0x7fffu + ((u >> 16) & 1u)) >> 16;
  return (u16)r;
}
__device__ __forceinline__ float bf2f(u16 h){ return __uint_as_float(((u32)h) << 16); }

// ---------- node norms (wave per node) ----------
__global__ __launch_bounds__(256) void norms_kernel(const float* __restrict__ x, float* __restrict__ nrm){
  int gw = (int)((blockIdx.x * 256u + threadIdx.x) >> 6);
  int lane = threadIdx.x & 63;
  if (gw >= ROWS) return;
  const float* r = x + (size_t)gw * NC;
  float s = 0.f;
#pragma unroll
  for (int j = 0; j < 3; ++j){ float v = r[lane + 64*j]; s += v*v; }
  s = wredsum(s);
  if (lane == 0) nrm[gw] = sqrtf(s) + 1e-8f;
}

// ---------- edge keys (wave per edge) ----------
__global__ __launch_bounds__(256) void keys_kernel(const float* __restrict__ x, const float* __restrict__ nrm,
                                                   u64* __restrict__ keys){
  int gw = (int)((blockIdx.x * 256u + threadIdx.x) >> 6);
  int lane = threadIdx.x & 63;
  if (gw >= NB * NE) return;
  int b = gw / NE, e = gw - b * NE;
  int u, v; edge_decode(e, u, v);
  const float* ru = x + ((size_t)b * NL + u) * NC;
  const float* rv = x + ((size_t)b * NL + v) * NC;
  float s = 0.f;
#pragma unroll
  for (int j = 0; j < 3; ++j){ s += ru[lane + 64*j] * rv[lane + 64*j]; }
  s = wredsum(s);
  if (lane == 0){
    float cosv = s / (nrm[b*NL + u] * nrm[b*NL + v]);
    float wgt = expf(1.0f - cosv);
    keys[(size_t)b*NE + e] = ((u64)__float_as_uint(wgt) << 32) | (u64)(u32)e;
  }
}

// ---------- per-image: Boruvka MST + CSR + single-wave BFS ----------
__global__ __launch_bounds__(1024) void tree_kernel(const u64* __restrict__ keys_g,
      int* __restrict__ order_g, int* __restrict__ parpos_g, int* __restrict__ pos_g,
      int* __restrict__ lvl_g, int* __restrict__ nlev_g){
  __shared__ __align__(16) char sm[62736];
  const int b = blockIdx.x;
  const int t = threadIdx.x;
  const int NT = 1024;
  u64* best   = (u64*)sm;            // [3136]  (phase B)
  u16* parent = (u16*)(sm + 25088);
  u16* comp   = (u16*)(sm + 31360);
  u16* mstU   = (u16*)(sm + 37632);
  u16* mstV   = (u16*)(sm + 43904);
  u16* adjl   = (u16*)(sm + 50176);  // [6270]
  u32* cnts   = (u32*)(sm + 62720);  // [4]
  u32* deg    = (u32*)sm;            // [3136]
  u32* offA   = (u32*)(sm + 12544);  // [3137]
  u32* aux    = (u32*)(sm + 25096);  // [1024]
  u16* bfs    = (u16*)sm;            // [3136] (phase D)
  u16* ppos   = (u16*)(sm + 6272);   // [3136]
  u16* posOf  = (u16*)(sm + 29192);  // [3136]

  const u64* kb = keys_g + (size_t)b * NE;
  for (int v = t; v < NL; v += NT) parent[v] = (u16)v;
  if (t == 0){ cnts[0] = 0; cnts[3] = 0xffffffffu; }
  __syncthreads();

  u32 gpass = 0;
  for (int round = 0; round < 24; ++round){
    // pointer-jumping compress; convergence checked every 2nd pass
    for (int it = 0; it < 12; ++it){
      bool ch = false;
      for (int v = t; v < NL; v += NT){
        u16 pv = parent[v]; u16 gpv = parent[pv];
        if (gpv != pv){ parent[v] = gpv; ch = true; }
      }
      bool docheck = (it & 1);
      if (docheck && ch) cnts[3] = gpass;
      __syncthreads();
      if (docheck){
        u32 seen = cnts[3];
        __syncthreads();
        u32 cur = gpass; ++gpass;
        if (seen != cur) break;
      }
    }
    for (int v = t; v < NL; v += NT){ comp[v] = parent[v]; best[v] = ~0ull; }
    if (t == 0) cnts[2] = 0;
    __syncthreads();
    for (int e = t; e < NE; e += NT){
      int u, v; edge_decode(e, u, v);
      u16 ru = comp[u], rv = comp[v];
      if (ru != rv){
        u64 k = kb[e];
        atomicMin(&best[ru], k);
        atomicMin(&best[rv], k);
      }
    }
    __syncthreads();
    for (int r = t; r < NL; r += NT){
      if (comp[r] == (u16)r){
        u64 bk = best[r];
        if (bk != ~0ull){
          int e = (int)(u32)bk; int u, v; edge_decode(e, u, v);
          u16 ru = comp[u], rv = comp[v];
          u16 other = (ru == (u16)r) ? rv : ru;
          bool mutual = (best[other] == bk);
          if (!mutual || (u16)r < other){
            parent[r] = other;
            u32 id = atomicAdd(&cnts[0], 1);
            mstU[id] = (u16)u; mstV[id] = (u16)v;
            cnts[2] = 1;
          }
        }
      }
    }
    __syncthreads();
    if (cnts[0] >= (u32)(NL - 1) || cnts[2] == 0) break;
  }
  __syncthreads();

  const int nm = NL - 1;
  for (int v = t; v < NL; v += NT) deg[v] = 0;
  __syncthreads();
  for (int i = t; i < nm; i += NT){ atomicAdd(&deg[mstU[i]], 1); atomicAdd(&deg[mstV[i]], 1); }
  __syncthreads();
  u32 loc[4]; u32 s = 0;
#pragma unroll
  for (int j = 0; j < 4; ++j){ int v = t*4 + j; u32 d = (v < NL) ? deg[v] : 0; loc[j] = s; s += d; }
  aux[t] = s; __syncthreads();
  for (int st = 1; st < 1024; st <<= 1){
    u32 mine = aux[t]; u32 add = (t >= st) ? aux[t - st] : 0; __syncthreads();
    aux[t] = mine + add; __syncthreads();
  }
  u32 base = (t > 0) ? aux[t-1] : 0;
#pragma unroll
  for (int j = 0; j < 4; ++j){ int v = t*4 + j; if (v < NL) offA[v] = base + loc[j]; }
  if (t == 0) offA[NL] = aux[1023];
  __syncthreads();
  for (int v = t; v < NL; v += NT) deg[v] = offA[v];
  __syncthreads();
  for (int i = t; i < nm; i += NT){
    int u = mstU[i], v = mstV[i];
    u32 p1 = atomicAdd(&deg[u], 1); adjl[p1] = (u16)v;
    u32 p2 = atomicAdd(&deg[v], 1); adjl[p2] = (u16)u;
  }
  __syncthreads();

  for (int v = t; v < NL; v += NT) posOf[v] = 0xffffu;
  __syncthreads();
  if (t == 0){
    bfs[0] = 0; ppos[0] = 0; posOf[0] = 0; cnts[1] = 1;
    lvl_g[b*3200 + 0] = 0; lvl_g[b*3200 + 1] = 1;
  }
  __syncthreads();

  // ---- single-wave BFS: wave 0 only, zero barriers (intra-wave lockstep).
  // Tree property: each unvisited node reachable from exactly one frontier
  // node -> posOf discovery race-free (same invariant the old version used).
  if (t < 64){
    int flo = 0, fhi = 1, d = 1;
    while (fhi < NL){
      for (int base2 = flo; base2 < fhi; base2 += 64){
        int idx = base2 + t;
        if (idx < fhi){
          int u = bfs[idx];
          int k0 = offA[u], k1 = offA[u + 1];
          for (int k = k0; k < k1; ++k){
            int v = adjl[k];
            if (posOf[v] == 0xffffu){
              u32 pos = atomicAdd(&cnts[1], 1);
              bfs[pos] = (u16)v; ppos[pos] = (u16)idx; posOf[v] = (u16)pos;
            }
          }
        }
        asm volatile("s_waitcnt lgkmcnt(0)" ::: "memory");
      }
      int nf = (int)cnts[1];
      if (t == 0) lvl_g[b*3200 + d + 1] = nf;
      flo = fhi; fhi = nf; ++d;
      if (nf == flo) break;
    }
    if (t == 0) nlev_g[b] = d;
  }
  __syncthreads();

  for (int p = t; p < NL; p += NT){
    order_g[b*NL + p] = (int)bfs[p];
    parpos_g[b*NL + p] = (int)ppos[p];
    pos_g[b*NL + p] = (int)posOf[p];
  }
}

// ---------- layernorm (wave per row); SPLIT -> bf16 hi|lo pair output ----------
template<int D, bool SPLIT>
__global__ __launch_bounds__(256) void ln_kernel(const float* __restrict__ in, const float* __restrict__ g,
                                                 const float* __restrict__ bt, void* __restrict__ outv){
  int gw = (int)((blockIdx.x * 256u + threadIdx.x) >> 6);
  int lane = threadIdx.x & 63;
  if (gw >= ROWS) return;
  constexpr int J = D / 64;
  const float* r = in + (size_t)gw * D;
  float v[J]; float s = 0.f;
#pragma unroll
  for (int j = 0; j < J; ++j){ v[j] = r[lane + 64*j]; s += v[j]; }
  s = wredsum(s);
  float mu = s * (1.0f / D);
  float q = 0.f;
#pragma unroll
  for (int j = 0; j < J; ++j){ float dd = v[j] - mu; q += dd*dd; }
  q = wredsum(q);
  float rs = rsqrtf(q * (1.0f / D) + 1e-5f);
  if (SPLIT){
    u16* o = (u16*)outv + (size_t)gw * (2*D);
#pragma unroll
    for (int j = 0; j < J; ++j){
      int dch = lane + 64*j;
      float y = (v[j] - mu) * rs * g[dch] + bt[dch];
      u16 hi = f2bf(y);
      o[dch] = hi; o[D + dch] = f2bf(y - bf2f(hi));
    }
  } else {
    float* o = (float*)outv + (size_t)gw * D;
#pragma unroll
    for (int j = 0; j < J; ++j){ int dch = lane + 64*j; o[dch] = (v[j] - mu) * rs * g[dch] + bt[dch]; }
  }
}

// ---------- weight split fp32 [N,K] -> bf16 [N, hi(K)|lo(K)] ----------
__global__ __launch_bounds__(256) void wsplit_kernel(const float* __restrict__ W, u16* __restrict__ o, int N, int K){
  int i = blockIdx.x * 256 + threadIdx.x;
  if (i >= N * K) return;
  int r = i / K, c = i - r * K;
  float v = W[i];
  u16 hi = f2bf(v);
  o[(size_t)r * 2 * K + c] = hi;
  o[(size_t)r * 2 * K + K + c] = f2bf(v - bf2f(hi));
}

// ---------- MFMA GEMM via hi/lo split; global_load_lds staging (pre-swizzled src).
// DUALOUT: N=768, cols<384 -> Cm (stride 384), cols>=384 -> C2 (stride 384). ----------
template<int BN, bool BIAS, int ACT, bool RESID, bool OSPLIT, bool DUALOUT>
__global__ __launch_bounds__(256) void mgemm_kernel(
    const u16* __restrict__ Ap, const u16* __restrict__ Wp,
    const float* __restrict__ bias, const float* __restrict__ resid,
    float* __restrict__ Cm, float* __restrict__ C2, int M, int N, int K){
  static_assert(BN == 64 || BN == 128, "BN");
  constexpr int WT = (BN == 128) ? 64 : 32;
  constexpr int NF = WT / 16;
  __shared__ short Ah[128*64], Al[128*64];
  __shared__ short Wh[BN*64], Wl[BN*64];
  const int bm = blockIdx.y * 128, bn = blockIdx.x * BN;
  const int tid = threadIdx.x, lane = tid & 63, wid = tid >> 6;
  const int wr = wid >> 1, wc = wid & 1;
  const int K2 = 2 * K;
  f4 acc[4][NF];
#pragma unroll
  for (int mf = 0; mf < 4; ++mf)
#pragma unroll
    for (int nf = 0; nf < NF; ++nf) acc[mf][nf] = (f4){0.f,0.f,0.f,0.f};

  for (int k0 = 0; k0 < K; k0 += 64){
#pragma unroll
    for (int j = 0; j < 4; ++j){
      int isb = wid*4 + j;
      int r = isb*8 + (lane >> 3);
      int c = lane & 7;
      const u16* src = Ap + (size_t)(bm + r) * K2 + k0 + ((c ^ (r & 7)) << 3);
      GL16(src,     &Ah[isb*512]);
      GL16(src + K, &Al[isb*512]);
    }
#pragma unroll
    for (int j = 0; j < BN/32; ++j){
      int isb = wid*(BN/32) + j;
      int r = isb*8 + (lane >> 3);
      int c = lane & 7;
      const u16* src = Wp + (size_t)(bn + r) * K2 + k0 + ((c ^ (r & 7)) << 3);
      GL16(src,     &Wh[isb*512]);
      GL16(src + K, &Wl[isb*512]);
    }
    __syncthreads();
#pragma unroll
    for (int kk = 0; kk < 2; ++kk){
      bh8 whf[NF], wlf[NF], ahf[4], alf[4];
#pragma unroll
      for (int nf = 0; nf < NF; ++nf){
        int rw = wc*WT + nf*16 + (lane & 15);
        int c = kk*4 + (lane >> 4);
        int ad = rw*64 + ((c ^ (rw & 7)) * 8);
        whf[nf] = *(const bh8*)&Wh[ad];
        wlf[nf] = *(const bh8*)&Wl[ad];
      }
#pragma unroll
      for (int mf = 0; mf < 4; ++mf){
        int ra = wr*64 + mf*16 + (lane & 15);
        int c = kk*4 + (lane >> 4);
        int ad = ra*64 + ((c ^ (ra & 7)) * 8);
        ahf[mf] = *(const bh8*)&Ah[ad];
        alf[mf] = *(const bh8*)&Al[ad];
      }
#pragma unroll
      for (int mf = 0; mf < 4; ++mf)
#pragma unroll
        for (int nf = 0; nf < NF; ++nf){
          acc[mf][nf] = __builtin_amdgcn_mfma_f32_16x16x32_bf16(ahf[mf], whf[nf], acc[mf][nf], 0, 0, 0);
          acc[mf][nf] = __builtin_amdgcn_mfma_f32_16x16x32_bf16(ahf[mf], wlf[nf], acc[mf][nf], 0, 0, 0);
          acc[mf][nf] = __builtin_amdgcn_mfma_f32_16x16x32_bf16(alf[mf], whf[nf], acc[mf][nf], 0, 0, 0);
        }
    }
    __syncthreads();
  }
  const int cb = bn + wc*WT;
#pragma unroll
  for (int mf = 0; mf < 4; ++mf){
    int row = bm + wr*64 + mf*16 + (lane >> 4)*4;
#pragma unroll
    for (int nf = 0; nf < NF; ++nf){
      int col = cb + nf*16 + (lane & 15);
#pragma unroll
      for (int r = 0; r < 4; ++r){
        float v = acc[mf][nf][r];
        if (BIAS) v += bias[col];
        if (ACT == 1) v = geluf(v);
        if (RESID) v += resid[(size_t)(row + r) * N + col];
        if (DUALOUT){
          float* op = (col < 384) ? Cm : C2;
          int oc = (col < 384) ? col : col - 384;
          op[(size_t)(row + r) * 384 + oc] = v;
        } else if (OSPLIT){
          u16* Gp = (u16*)Cm;
          u16 hi = f2bf(v);
          Gp[(size_t)(row + r) * (2*N) + col] = hi;
          Gp[(size_t)(row + r) * (2*N) + N + col] = f2bf(v - bf2f(hi));
        } else {
          Cm[(size_t)(row + r) * N + col] = v;
        }
      }
    }
  }
}

// ---------- depthwise conv 3x3 SAME + bias + silu ----------
__global__ __launch_bounds__(256) void conv_kernel(const float* __restrict__ xs, const float* __restrict__ cw,
                                                   const float* __restrict__ cb, float* __restrict__ u){
  int idx = blockIdx.x * 256 + threadIdx.x;
  if (idx >= ROWS * 96) return;
  int q = idx % 96; int l = idx / 96;
  int b = l / NL; int hw = l - b * NL; int h = hw / 56; int wc = hw - h * 56;
  int c4 = q * 4;
  float4 acc = *(const float4*)(cb + c4);
#pragma unroll
  for (int kh = 0; kh < 3; ++kh){
    int hh = h + kh - 1; if (hh < 0 || hh >= 56) continue;
#pragma unroll
    for (int kw = 0; kw < 3; ++kw){
      int wwc = wc + kw - 1; if (wwc < 0 || wwc >= 56) continue;
      float4 iv = *(const float4*)(xs + ((size_t)(b * NL + hh*56 + wwc)) * DIN + c4);
      float4 wv = *(const float4*)(cw + (size_t)(kh*3 + kw) * DIN + c4);
      acc.x += iv.x * wv.x; acc.y += iv.y * wv.y; acc.z += iv.z * wv.z; acc.w += iv.w * wv.w;
    }
  }
  float4 o; o.x = siluf(acc.x); o.y = siluf(acc.y); o.z = siluf(acc.z); o.w = siluf(acc.w);
  *(float4*)(u + (size_t)l * DIN + c4) = o;
}

// ---------- x_proj + dt_proj + softplus + w/feat (wave per row), BFS-pos output ----------
__global__ __launch_bounds__(256) void xdbl_kernel(const float* __restrict__ u,
    const float* __restrict__ xpw, const float* __restrict__ dtw_g,
    const float* __restrict__ dtb, const float* __restrict__ alog, const int* __restrict__ pos_g,
    float* __restrict__ wout, float* __restrict__ fout, float* __restrict__ csout){
  __shared__ float xw[14*384];
  __shared__ float dw[384*12];
  __shared__ float db[384];
  __shared__ float An[384];
  int t = threadIdx.x;
  for (int i = t; i < 14*384; i += 256) xw[i] = xpw[i];
  for (int i = t; i < 384*12; i += 256) dw[i] = dtw_g[i];
  for (int i = t; i < 384; i += 256){ db[i] = dtb[i]; An[i] = -expf(alog[i]); }
  __syncthreads();
  int wave = t >> 6, lane = t & 63;
  int row0 = blockIdx.x * 16 + wave * 4;
  for (int rr = 0; rr < 4; ++rr){
    int m = row0 + rr;
    int b = m / NL;
    int pos = pos_g[m];
    size_t orow = ((size_t)b * NL + pos) * DIN;
    const float* ur = u + (size_t)m * DIN;
    float u6[6];
#pragma unroll
    for (int j = 0; j < 6; ++j) u6[j] = ur[lane + 64*j];
    float xd[14];
#pragma unroll
    for (int r = 0; r < 14; ++r){
      float p = 0.f;
#pragma unroll
      for (int j = 0; j < 6; ++j) p += u6[j] * xw[r*384 + lane + 64*j];
      xd[r] = wredsum(p);
    }
    float Bs = xd[12], Cv = xd[13];
#pragma unroll
    for (int j = 0; j < 6; ++j){
      int dch = lane + 64*j;
      float pre = db[dch];
#pragma unroll
      for (int r = 0; r < 12; ++r) pre += xd[r] * dw[dch*12 + r];
      float dts = sofplus(pre);
      float wv = expf(dts * An[dch]);
      float fv = dts * Bs * u6[j];
      wout[orow + dch] = wv;
      fout[orow + dch] = fv;
    }
    if (lane == 0) csout[m] = Cv;
  }
}

// ---------- w transpose: [b][pos][384] -> planar [b][ch][pos] (64x64 LDS tiles) ----------
__global__ __launch_bounds__(256) void wtr_kernel(const float* __restrict__ in, float* __restrict__ out){
  __shared__ float tile[64][65];
  int blk = blockIdx.x;                  // 8 * 49 * 6
  int b = blk / (49*6);
  int r = blk - b*(49*6);
  int pt = r / 6, ct = r - pt*6;         // pos tile, channel tile
  int t = threadIdx.x;
  int tr = t >> 6, lane = t & 63;
  const float* src = in + ((size_t)b*NL + (size_t)pt*64) * DIN + ct*64;
#pragma unroll
  for (int k = 0; k < 16; ++k){
    int rr = tr + k*4;
    tile[rr][lane] = src[(size_t)rr*DIN + lane];
  }
  __syncthreads();
  float* dst = out + ((size_t)b*DIN + (size_t)ct*64) * NL + (size_t)pt*64;
#pragma unroll
  for (int k = 0; k < 16; ++k){
    int cc = tr + k*4;
    dst[(size_t)cc*NL + lane] = tile[lane][cc];
  }
}

// ---------- tree sweep v7: planar channel planes + PLANAR w stream (contiguous
// 256B window loads). One wave per channel, zero inter-wave barriers. ----------
__global__ __launch_bounds__(256) void sweep7_kernel(const float* __restrict__ featp, const float* __restrict__ wtr,
    float* __restrict__ Hp, const int* __restrict__ parpos_g,
    const int* __restrict__ lvl_g, const int* __restrict__ nlev_g){
  __shared__ float S[4*NL];    // 4 planar channel planes, 50176B -> 3 blocks/CU
  int blk = blockIdx.x;
  int b = blk & 7, q = blk >> 3;   // tree b pinned to XCD b
  int t = threadIdx.x, lane = t & 63, wv = t >> 6;
  int nl = nlev_g[b];
  const int* pg = parpos_g + b*NL;
  const int* lg = lvl_g + b*3200;
  const float* fbase = featp + (size_t)b*NL*DIN + q*4;
  const float* wbase = wtr + ((size_t)b*DIN + q*4 + wv) * NL;   // planar: this wave's channel row
  float*       hbase = Hp    + (size_t)b*NL*DIN + q*4;
  for (int i = t; i < NL; i += 256){
    float4 f = *(const float4*)(fbase + (size_t)i*DIN);
    S[0*NL + i] = f.x; S[1*NL + i] = f.y; S[2*NL + i] = f.z; S[3*NL + i] = f.w;
  }
  __syncthreads();
  float* Sp = &S[wv*NL];   // this wave's plane; no other wave touches it

  // ---- up-sweep: levels nl-1 .. 1, 64-wide windows, no barriers ----
  if (nl >= 2){
    int d  = nl - 1;
    int lo = lg[d], hi = lg[d+1];
    int nlo = (d >= 2) ? lg[d-1] : 0;
    float wc = 0.f; int ppc = 0;
    { int p = lo + lane; if (p < hi){ wc = wbase[p]; ppc = pg[p]; } }
    int base = lo;
    while (1){
      int d2 = d, nb = base + 64, nhi = hi, nlo2 = nlo, lo2 = lo;
      bool lvlchange = false;
      if (nb >= hi){
        d2 = d - 1; lvlchange = true;
        if (d2 >= 1){
          nb = nlo; nhi = lo; lo2 = nlo;
          nlo2 = (d2 >= 2) ? lg[d2-1] : 0;
        }
      }
      float wn = 0.f; int ppn = 0;
      if (d2 >= 1){ int pn = nb + lane; if (pn < nhi){ wn = wbase[pn]; ppn = pg[pn]; } }
      int p = base + lane;
      if (p < hi){
        float s = Sp[p];
        atomicAdd(&Sp[ppc], wc * s);
      }
      if (lvlchange){
        asm volatile("s_waitcnt lgkmcnt(0)" ::: "memory");   // intra-wave LDS ordering only
      }
      if (d2 < 1) break;
      d = d2; base = nb; hi = nhi; lo = lo2; nlo = nlo2; wc = wn; ppc = ppn;
    }
  }

  // ---- down-sweep: levels 1 .. nl-1 ----
  if (nl >= 2){
    int d = 1;
    int lo = lg[1], hi = lg[2];
    int hi2 = (nl >= 3) ? lg[3] : 0;
    float wc = 0.f; int ppc = 0;
    { int p = lo + lane; if (p < hi){ wc = wbase[p]; ppc = pg[p]; } }
    int base = lo;
    while (1){
      int d2 = d, nb = base + 64, nhi = hi, hi2n = hi2;
      bool lvlchange = false;
      if (nb >= hi){
        d2 = d + 1; lvlchange = true;
        nb = hi; nhi = hi2;
        hi2n = (d2 + 2 <= nl) ? lg[d2+2] : 0;
      }
      float wn = 0.f; int ppn = 0;
      if (d2 <= nl-1){ int pn = nb + lane; if (pn < nhi){ wn = wbase[pn]; ppn = pg[pn]; } }
      int p = base + lane;
      if (p < hi){
        float s = Sp[p]; float h = Sp[ppc];
        Sp[p] = s + wc * (h - wc * s);
      }
      if (lvlchange){
        asm volatile("s_waitcnt lgkmcnt(0)" ::: "memory");
      }
      if (d2 > nl-1) break;
      d = d2; base = nb; hi = nhi; hi2 = hi2n; wc = wn; ppc = ppn;
    }
  }

  __syncthreads();
  for (int i = t; i < NL; i += 256){
    float4 o;
    o.x = S[0*NL + i]; o.y = S[1*NL + i]; o.z = S[2*NL + i]; o.w = S[3*NL + i];
    *(float4*)(hbase + (size_t)i*DIN) = o;
  }
}

// ---------- y = Cs*H + Ds*u -> LN -> * silu(z) -> bf16 hi|lo pair (pos-row input) ----------
__global__ __launch_bounds__(256) void ynorm_kernel(const float* __restrict__ Hp, const float* __restrict__ u,
    const float* __restrict__ z, const float* __restrict__ Cs, const int* __restrict__ order_g,
    const float* __restrict__ Ds, const float* __restrict__ g, const float* __restrict__ bt,
    u16* __restrict__ out){
  int gw = (int)((blockIdx.x * 256u + threadIdx.x) >> 6);   // pos-row
  int lane = threadIdx.x & 63;
  if (gw >= ROWS) return;
  int b = gw / NL;
  int node = order_g[gw];
  size_t nrow = (size_t)b * NL + node;
  float Cv = Cs[nrow];
  const float* hr = Hp + (size_t)gw * DIN;
  const float* ur = u + nrow * DIN;
  const float* zr = z + nrow * DIN;
  float y[6]; float s = 0.f;
#pragma unroll
  for (int j = 0; j < 6; ++j){
    int dch = lane + 64*j;
    y[j] = Cv * hr[dch] + Ds[dch] * ur[dch];
    s += y[j];
  }
  s = wredsum(s);
  float mu = s * (1.0f / DIN);
  float q = 0.f;
#pragma unroll
  for (int j = 0; j < 6; ++j){ float dd = y[j] - mu; q += dd*dd; }
  q = wredsum(q);
  float rs = rsqrtf(q * (1.0f / DIN) + 1e-5f);
  u16* o = out + nrow * (2*DIN);
#pragma unroll
  for (int j = 0; j < 6; ++j){
    int dch = lane + 64*j;
    float yn = (y[j] - mu) * rs * g[dch] + bt[dch];
    float v = yn * siluf(zr[dch]);
    u16 hi = f2bf(v);
    o[dch] = hi; o[DIN + dch] = f2bf(v - bf2f(hi));
  }
}

// ---------- host orchestration ----------
extern "C" void kernel_launch(void* const* d_in, const int* in_sizes, int n_in,
                              void* d_out, int out_size, void* d_ws, size_t ws_size,
                              hipStream_t stream){
  const float* x_in       = (const float*)d_in[0];
  const float* norm1_w    = (const float*)d_in[1];
  const float* norm1_b    = (const float*)d_in[2];
  const float* in_proj_w  = (const float*)d_in[3];
  const float* conv_w     = (const float*)d_in[4];
  const float* conv_b     = (const float*)d_in[5];
  const float* x_proj_w   = (const float*)d_in[6];
  const float* dt_proj_w  = (const float*)d_in[7];
  const float* dt_proj_b  = (const float*)d_in[8];
  const float* A_log      = (const float*)d_in[9];
  const float* Ds         = (const float*)d_in[10];
  const float* out_norm_w = (const float*)d_in[11];
  const float* out_norm_b = (const float*)d_in[12];
  const float* out_proj_w = (const float*)d_in[13];
  const float* norm2_w    = (const float*)d_in[14];
  const float* norm2_b    = (const float*)d_in[15];
  const float* fc1_w      = (const float*)d_in[16];
  const float* fc1_b      = (const float*)d_in[17];
  const float* fc2_w      = (const float*)d_in[18];
  const float* fc2_b      = (const float*)d_in[19];
  const float* fnorm_w    = (const float*)d_in[20];
  const float* fnorm_b    = (const float*)d_in[21];

  float* ws = (float*)d_ws;
  float* X     = ws + 0;
  u16*   bufAh = (u16*)(ws + 4816896);
  float* bufZ  = ws + 9633792;
  float* bufW  = ws + 19267584;
  float* bufU  = ws + 28901376;
  float* bufF  = ws + 38535168;
  u16*   Gp    = (u16*)bufU;
  float* Csb   = ws + 48168960;
  int*   ordg  = (int*)(ws + 48194048);
  int*   ppg   = (int*)(ws + 48219136);
  int*   lvlg  = (int*)(ws + 48244224);
  int*   nlvg  = (int*)(ws + 48269824);
  u64*   keysg = (u64*)(ws + 48269832);
  float* nrm   = ws + 48368392;
  u16*   ipWp  = (u16*)(ws + 48393480);
  u16*   opWp  = (u16*)(ws + 48540936);
  u16*   fc1Wp = (u16*)(ws + 48614664);
  u16*   fc2Wp = (u16*)(ws + 48762120);
  int*   posg  = (int*)(ws + 48909576);
  float* wtrp  = ws + 48934664;          // planar w [b][384][NL], 9633792 f

  hipMemcpyAsync(X, x_in, (size_t)ROWS * NC * sizeof(float), hipMemcpyDeviceToDevice, stream);

  for (int i = 0; i < 2; ++i){
    wsplit_kernel<<<(768*192+255)/256, 256, 0, stream>>>(in_proj_w + (size_t)i*NHID*NC, ipWp, 768, 192);
    wsplit_kernel<<<(192*384+255)/256, 256, 0, stream>>>(out_proj_w + (size_t)i*NC*DIN, opWp, 192, 384);
    wsplit_kernel<<<(768*192+255)/256, 256, 0, stream>>>(fc1_w + (size_t)i*NHID*NC, fc1Wp, 768, 192);
    wsplit_kernel<<<(192*768+255)/256, 256, 0, stream>>>(fc2_w + (size_t)i*NC*NHID, fc2Wp, 192, 768);

    norms_kernel<<<ROWS/4, 256, 0, stream>>>(X, nrm);
    keys_kernel<<<(NB*NE)/4, 256, 0, stream>>>(X, nrm, keysg);
    tree_kernel<<<NB, 1024, 0, stream>>>(keysg, ordg, ppg, posg, lvlg, nlvg);

    ln_kernel<192,true><<<ROWS/4, 256, 0, stream>>>(X, norm1_w + i*NC, norm1_b + i*NC, bufAh);
    // fused in_proj: N=768, xs half -> bufF, z half -> bufZ
    mgemm_kernel<128,false,0,false,false,true><<<dim3(6,196), 256, 0, stream>>>(bufAh, ipWp, nullptr, nullptr, bufF, bufZ, ROWS, 768, 192);

    conv_kernel<<<(ROWS*96)/256, 256, 0, stream>>>(bufF, conv_w + (size_t)i*9*DIN, conv_b + i*DIN, bufU);

    // w/feat written in BFS-pos order (bufW = wperm, bufF = featperm)
    xdbl_kernel<<<ROWS/16, 256, 0, stream>>>(bufU, x_proj_w + (size_t)i*14*DIN, dt_proj_w + (size_t)i*DIN*12,
                                             dt_proj_b + i*DIN, A_log + i*DIN, posg, bufW, bufF, Csb);

    // transpose w to planar [b][ch][pos]
    wtr_kernel<<<8*49*6, 256, 0, stream>>>(bufW, wtrp);

    sweep7_kernel<<<NB*96, 256, 0, stream>>>(bufF, wtrp, bufF, ppg, lvlg, nlvg);

    ynorm_kernel<<<ROWS/4, 256, 0, stream>>>(bufF, bufU, bufZ, Csb, ordg, Ds + i*DIN,
                                             out_norm_w + i*DIN, out_norm_b + i*DIN, (u16*)bufW);

    mgemm_kernel<64,false,0,true,false,false><<<dim3(3,196), 256, 0, stream>>>((u16*)bufW, opWp, nullptr, X, X, nullptr, ROWS, 192, 384);

    ln_kernel<192,true><<<ROWS/4, 256, 0, stream>>>(X, norm2_w + i*NC, norm2_b + i*NC, bufAh);
    mgemm_kernel<128,true,1,false,true,false><<<dim3(6,196), 256, 0, stream>>>(bufAh, fc1Wp, fc1_b + i*NHID, nullptr, (float*)Gp, nullptr, ROWS, NHID, 192);
    mgemm_kernel<64,true,0,true,false,false><<<dim3(3,196), 256, 0, stream>>>(Gp, fc2Wp, fc2_b + i*NC, X, X, nullptr, ROWS, 192, 768);
  }

  ln_kernel<192,false><<<ROWS/4, 256, 0, stream>>>(X, fnorm_w, fnorm_b, d_out);
}

// Round 12
// 1682.357 us; speedup vs baseline: 1.0387x; 1.0262x over previous
//
#include <hip/hip_runtime.h>
#include <math.h>

#define NB 8
#define NC 192
#define DIN 384
#define NL 3136
#define ROWS (NB*NL)     // 25088
#define NE 6160
#define NHID 768

typedef unsigned short u16;
typedef unsigned int u32;
typedef unsigned long long u64;
typedef __attribute__((ext_vector_type(8))) short bh8;
typedef __attribute__((ext_vector_type(4))) float f4;

// global_load_lds width=16: wave-uniform LDS base + lane*16; per-lane global src.
typedef __attribute__((address_space(1))) const void gl_as1;
typedef __attribute__((address_space(3))) void gl_as3;
#define GL16(g, l) __builtin_amdgcn_global_load_lds((gl_as1*)(const void*)(g), (gl_as3*)(void*)(l), 16, 0, 0)

// ---------- helpers ----------
__device__ __forceinline__ float wredsum(float v){
  v += __shfl_xor(v, 1, 64); v += __shfl_xor(v, 2, 64); v += __shfl_xor(v, 4, 64);
  v += __shfl_xor(v, 8, 64); v += __shfl_xor(v, 16, 64); v += __shfl_xor(v, 32, 64);
  return v;
}
__device__ __forceinline__ void edge_decode(int e, int& u, int& v){
  if (e < 3080){ int h = e/55, w = e - h*55; u = h*56 + w; v = u + 1; }
  else { int e2 = e - 3080; int h = e2/56, w = e2 - h*56; u = h*56 + w; v = u + 56; }
}
__device__ __forceinline__ float siluf(float x){ return x / (1.0f + expf(-x)); }
__device__ __forceinline__ float sofplus(float x){ return fmaxf(x, 0.0f) + log1pf(expf(-fabsf(x))); }
__device__ __forceinline__ float geluf(float x){ return 0.5f * x * (1.0f + erff(x * 0.70710678118654752f)); }
__device__ __forceinline__ u16 f2bf(float x){
  u32 u = __float_as_uint(x);
  u32 r = (u + 0x7fffu + ((u >> 16) & 1u)) >> 16;
  return (u16)r;
}
__device__ __forceinline__ float bf2f(u16 h){ return __uint_as_float(((u32)h) << 16); }

// ---------- node norms (wave per node) ----------
__global__ __launch_bounds__(256) void norms_kernel(const float* __restrict__ x, float* __restrict__ nrm){
  int gw = (int)((blockIdx.x * 256u + threadIdx.x) >> 6);
  int lane = threadIdx.x & 63;
  if (gw >= ROWS) return;
  const float* r = x + (size_t)gw * NC;
  float s = 0.f;
#pragma unroll
  for (int j = 0; j < 3; ++j){ float v = r[lane + 64*j]; s += v*v; }
  s = wredsum(s);
  if (lane == 0) nrm[gw] = sqrtf(s) + 1e-8f;
}

// ---------- edge keys (wave per edge) ----------
__global__ __launch_bounds__(256) void keys_kernel(const float* __restrict__ x, const float* __restrict__ nrm,
                                                   u64* __restrict__ keys){
  int gw = (int)((blockIdx.x * 256u + threadIdx.x) >> 6);
  int lane = threadIdx.x & 63;
  if (gw >= NB * NE) return;
  int b = gw / NE, e = gw - b * NE;
  int u, v; edge_decode(e, u, v);
  const float* ru = x + ((size_t)b * NL + u) * NC;
  const float* rv = x + ((size_t)b * NL + v) * NC;
  float s = 0.f;
#pragma unroll
  for (int j = 0; j < 3; ++j){ s += ru[lane + 64*j] * rv[lane + 64*j]; }
  s = wredsum(s);
  if (lane == 0){
    float cosv = s / (nrm[b*NL + u] * nrm[b*NL + v]);
    float wgt = expf(1.0f - cosv);
    keys[(size_t)b*NE + e] = ((u64)__float_as_uint(wgt) << 32) | (u64)(u32)e;
  }
}

// ---------- per-image: Boruvka MST (batched) + adjl4 + posOf-free single-wave BFS ----------
__global__ __launch_bounds__(1024) void tree_kernel(const u64* __restrict__ keys_g,
      int* __restrict__ order_g, int* __restrict__ parpos_g, int* __restrict__ pos_g,
      int* __restrict__ lvl_g, int* __restrict__ nlev_g){
  __shared__ __align__(16) char sm[62736];
  const int b = blockIdx.x;
  const int t = threadIdx.x;
  const int NT = 1024;
  // Boruvka phase:
  u64* best   = (u64*)sm;            // [3136] @0     (25088)
  u16* parent = (u16*)(sm + 25088);  // [3136] (6272)
  u16* comp   = (u16*)(sm + 31360);  // [3136] (6272)
  u16* mstU   = (u16*)(sm + 37632);  // [3136] (6272)
  u16* mstV   = (u16*)(sm + 43904);  // [3136] (6272)
  u32* cnts   = (u32*)(sm + 56448);  // [4]
  // Adjacency/BFS phase (aliases over dead regions):
  u16* adjl4  = (u16*)sm;            // [3136*4] @0 (25088, over best)
  u32* deg    = (u32*)(sm + 25088);  // [3136] (12544, over parent+comp)
  u32* fr     = (u32*)(sm + 37632);  // [3136] (12544, over mstU+mstV): node | pnode<<16
  u16* ppos   = (u16*)(sm + 50176);  // [3136] (6272)

  const u64* kb = keys_g + (size_t)b * NE;
  for (int v = t; v < NL; v += NT) parent[v] = (u16)v;
  if (t == 0){ cnts[0] = 0; cnts[3] = 0xffffffffu; }
  __syncthreads();

  u32 gpass = 0;
  for (int round = 0; round < 24; ++round){
    // batched pointer-jumping compress; convergence checked every 2nd pass
    for (int it = 0; it < 12; ++it){
      int vv[4]; u16 pv[4]; int nb2 = 0;
#pragma unroll
      for (int j = 0; j < 4; ++j){ int v = t + j*NT; if (v < NL){ vv[nb2] = v; pv[nb2] = parent[v]; ++nb2; } }
      u16 gp[4];
      for (int j = 0; j < nb2; ++j) gp[j] = parent[pv[j]];
      bool ch = false;
      for (int j = 0; j < nb2; ++j){ if (gp[j] != pv[j]){ parent[vv[j]] = gp[j]; ch = true; } }
      bool docheck = (it & 1);
      if (docheck && ch) cnts[3] = gpass;
      __syncthreads();
      if (docheck){
        u32 seen = cnts[3];
        __syncthreads();
        u32 cur = gpass; ++gpass;
        if (seen != cur) break;
      }
    }
    for (int v = t; v < NL; v += NT){ comp[v] = parent[v]; best[v] = ~0ull; }
    if (t == 0) cnts[2] = 0;
    __syncthreads();
    // batched edge scan
    {
      int ee[7]; int eu[7], ev[7]; u16 cu[7], cv[7]; u64 kk[7]; int nb2 = 0;
#pragma unroll
      for (int j = 0; j < 7; ++j){
        int e = t + j*NT;
        if (e < NE){ ee[nb2] = e; int u, v; edge_decode(e, u, v); eu[nb2] = u; ev[nb2] = v; ++nb2; }
      }
      for (int j = 0; j < nb2; ++j){ cu[j] = comp[eu[j]]; cv[j] = comp[ev[j]]; }
      for (int j = 0; j < nb2; ++j){ kk[j] = kb[ee[j]]; }
      for (int j = 0; j < nb2; ++j){
        if (cu[j] != cv[j]){
          atomicMin(&best[cu[j]], kk[j]);
          atomicMin(&best[cv[j]], kk[j]);
        }
      }
    }
    __syncthreads();
    // batched root-select + merge
    {
      int rr[4]; u64 bk[4]; int nb2 = 0;
#pragma unroll
      for (int j = 0; j < 4; ++j){ int r = t + j*NT; if (r < NL){ rr[nb2] = r; ++nb2; } }
      u16 cr[4];
      for (int j = 0; j < nb2; ++j) cr[j] = comp[rr[j]];
      for (int j = 0; j < nb2; ++j) bk[j] = (cr[j] == (u16)rr[j]) ? best[rr[j]] : ~0ull;
      int uu[4], vv2[4]; u16 ru2[4], rv2[4];
      for (int j = 0; j < nb2; ++j){
        if (bk[j] != ~0ull){ int e = (int)(u32)bk[j]; edge_decode(e, uu[j], vv2[j]); }
      }
      for (int j = 0; j < nb2; ++j){
        if (bk[j] != ~0ull){ ru2[j] = comp[uu[j]]; rv2[j] = comp[vv2[j]]; }
      }
      for (int j = 0; j < nb2; ++j){
        if (bk[j] != ~0ull){
          int r = rr[j];
          u16 other = (ru2[j] == (u16)r) ? rv2[j] : ru2[j];
          bool mutual = (best[other] == bk[j]);
          if (!mutual || (u16)r < other){
            parent[r] = other;
            u32 id = atomicAdd(&cnts[0], 1);
            mstU[id] = (u16)uu[j]; mstV[id] = (u16)vv2[j];
            cnts[2] = 1;
          }
        }
      }
    }
    __syncthreads();
    if (cnts[0] >= (u32)(NL - 1) || cnts[2] == 0) break;
  }
  __syncthreads();

  // ---- fixed-degree adjacency adjl4[node][4] (grid degree <= 4), 0xffff pad ----
  const int nm = NL - 1;
  for (int v = t; v < NL; v += NT){
    deg[v] = 0;
    *(u64*)&adjl4[v*4] = 0xffffffffffffffffull;
  }
  __syncthreads();
  {
    int uu[4], vv2[4]; int nb2 = 0;
#pragma unroll
    for (int j = 0; j < 4; ++j){
      int i = t + j*NT;
      if (i < nm){ uu[nb2] = mstU[i]; vv2[nb2] = mstV[i]; ++nb2; }
    }
    for (int j = 0; j < nb2; ++j){
      u32 s1 = atomicAdd(&deg[uu[j]], 1); adjl4[uu[j]*4 + s1] = (u16)vv2[j];
      u32 s2 = atomicAdd(&deg[vv2[j]], 1); adjl4[vv2[j]*4 + s2] = (u16)uu[j];
    }
  }
  __syncthreads();

  // ---- posOf-free single-wave BFS: frontier = node | pnode<<16 ----
  if (t == 0){
    fr[0] = 0u | (0xffffu << 16);
    ppos[0] = 0;
    cnts[1] = 1;
    lvl_g[b*3200 + 0] = 0; lvl_g[b*3200 + 1] = 1;
  }
  __syncthreads();
  if (t < 64){
    int flo = 0, fhi = 1, d = 1;
    while (fhi < NL){
      for (int base2 = flo; base2 < fhi; base2 += 64){
        int idx = base2 + t;
        if (idx < fhi){
          u32 f = fr[idx];
          int u = (int)(f & 0xffffu), pn = (int)(f >> 16);
          u64 four = *(const u64*)&adjl4[u*4];
#pragma unroll
          for (int j = 0; j < 4; ++j){
            int v = (int)((four >> (16*j)) & 0xffffu);
            if (v != 0xffff && v != pn){
              u32 pos = atomicAdd(&cnts[1], 1);
              fr[pos] = (u32)v | ((u32)u << 16);
              ppos[pos] = (u16)idx;
            }
          }
        }
        asm volatile("s_waitcnt lgkmcnt(0)" ::: "memory");
      }
      int nf = (int)cnts[1];
      if (t == 0) lvl_g[b*3200 + d + 1] = nf;
      flo = fhi; fhi = nf; ++d;
      if (nf == flo) break;
    }
    if (t == 0) nlev_g[b] = d;
  }
  __syncthreads();

  for (int p = t; p < NL; p += NT){
    u32 f = fr[p];
    int node = (int)(f & 0xffffu);
    order_g[b*NL + p] = node;
    parpos_g[b*NL + p] = (int)ppos[p];
    pos_g[b*NL + node] = p;
  }
}

// ---------- layernorm (wave per row); SPLIT -> bf16 hi|lo pair output ----------
template<int D, bool SPLIT>
__global__ __launch_bounds__(256) void ln_kernel(const float* __restrict__ in, const float* __restrict__ g,
                                                 const float* __restrict__ bt, void* __restrict__ outv){
  int gw = (int)((blockIdx.x * 256u + threadIdx.x) >> 6);
  int lane = threadIdx.x & 63;
  if (gw >= ROWS) return;
  constexpr int J = D / 64;
  const float* r = in + (size_t)gw * D;
  float v[J]; float s = 0.f;
#pragma unroll
  for (int j = 0; j < J; ++j){ v[j] = r[lane + 64*j]; s += v[j]; }
  s = wredsum(s);
  float mu = s * (1.0f / D);
  float q = 0.f;
#pragma unroll
  for (int j = 0; j < J; ++j){ float dd = v[j] - mu; q += dd*dd; }
  q = wredsum(q);
  float rs = rsqrtf(q * (1.0f / D) + 1e-5f);
  if (SPLIT){
    u16* o = (u16*)outv + (size_t)gw * (2*D);
#pragma unroll
    for (int j = 0; j < J; ++j){
      int dch = lane + 64*j;
      float y = (v[j] - mu) * rs * g[dch] + bt[dch];
      u16 hi = f2bf(y);
      o[dch] = hi; o[D + dch] = f2bf(y - bf2f(hi));
    }
  } else {
    float* o = (float*)outv + (size_t)gw * D;
#pragma unroll
    for (int j = 0; j < J; ++j){ int dch = lane + 64*j; o[dch] = (v[j] - mu) * rs * g[dch] + bt[dch]; }
  }
}

// ---------- weight split fp32 [N,K] -> bf16 [N, hi(K)|lo(K)] ----------
__global__ __launch_bounds__(256) void wsplit_kernel(const float* __restrict__ W, u16* __restrict__ o, int N, int K){
  int i = blockIdx.x * 256 + threadIdx.x;
  if (i >= N * K) return;
  int r = i / K, c = i - r * K;
  float v = W[i];
  u16 hi = f2bf(v);
  o[(size_t)r * 2 * K + c] = hi;
  o[(size_t)r * 2 * K + K + c] = f2bf(v - bf2f(hi));
}

// ---------- MFMA GEMM via hi/lo split; global_load_lds staging (pre-swizzled src).
// DUALOUT: N=768, cols<384 -> Cm (stride 384), cols>=384 -> C2 (stride 384). ----------
template<int BN, bool BIAS, int ACT, bool RESID, bool OSPLIT, bool DUALOUT>
__global__ __launch_bounds__(256) void mgemm_kernel(
    const u16* __restrict__ Ap, const u16* __restrict__ Wp,
    const float* __restrict__ bias, const float* __restrict__ resid,
    float* __restrict__ Cm, float* __restrict__ C2, int M, int N, int K){
  static_assert(BN == 64 || BN == 128, "BN");
  constexpr int WT = (BN == 128) ? 64 : 32;
  constexpr int NF = WT / 16;
  __shared__ short Ah[128*64], Al[128*64];
  __shared__ short Wh[BN*64], Wl[BN*64];
  const int bm = blockIdx.y * 128, bn = blockIdx.x * BN;
  const int tid = threadIdx.x, lane = tid & 63, wid = tid >> 6;
  const int wr = wid >> 1, wc = wid & 1;
  const int K2 = 2 * K;
  f4 acc[4][NF];
#pragma unroll
  for (int mf = 0; mf < 4; ++mf)
#pragma unroll
    for (int nf = 0; nf < NF; ++nf) acc[mf][nf] = (f4){0.f,0.f,0.f,0.f};

  for (int k0 = 0; k0 < K; k0 += 64){
#pragma unroll
    for (int j = 0; j < 4; ++j){
      int isb = wid*4 + j;
      int r = isb*8 + (lane >> 3);
      int c = lane & 7;
      const u16* src = Ap + (size_t)(bm + r) * K2 + k0 + ((c ^ (r & 7)) << 3);
      GL16(src,     &Ah[isb*512]);
      GL16(src + K, &Al[isb*512]);
    }
#pragma unroll
    for (int j = 0; j < BN/32; ++j){
      int isb = wid*(BN/32) + j;
      int r = isb*8 + (lane >> 3);
      int c = lane & 7;
      const u16* src = Wp + (size_t)(bn + r) * K2 + k0 + ((c ^ (r & 7)) << 3);
      GL16(src,     &Wh[isb*512]);
      GL16(src + K, &Wl[isb*512]);
    }
    __syncthreads();
#pragma unroll
    for (int kk = 0; kk < 2; ++kk){
      bh8 whf[NF], wlf[NF], ahf[4], alf[4];
#pragma unroll
      for (int nf = 0; nf < NF; ++nf){
        int rw = wc*WT + nf*16 + (lane & 15);
        int c = kk*4 + (lane >> 4);
        int ad = rw*64 + ((c ^ (rw & 7)) * 8);
        whf[nf] = *(const bh8*)&Wh[ad];
        wlf[nf] = *(const bh8*)&Wl[ad];
      }
#pragma unroll
      for (int mf = 0; mf < 4; ++mf){
        int ra = wr*64 + mf*16 + (lane & 15);
        int c = kk*4 + (lane >> 4);
        int ad = ra*64 + ((c ^ (ra & 7)) * 8);
        ahf[mf] = *(const bh8*)&Ah[ad];
        alf[mf] = *(const bh8*)&Al[ad];
      }
#pragma unroll
      for (int mf = 0; mf < 4; ++mf)
#pragma unroll
        for (int nf = 0; nf < NF; ++nf){
          acc[mf][nf] = __builtin_amdgcn_mfma_f32_16x16x32_bf16(ahf[mf], whf[nf], acc[mf][nf], 0, 0, 0);
          acc[mf][nf] = __builtin_amdgcn_mfma_f32_16x16x32_bf16(ahf[mf], wlf[nf], acc[mf][nf], 0, 0, 0);
          acc[mf][nf] = __builtin_amdgcn_mfma_f32_16x16x32_bf16(alf[mf], whf[nf], acc[mf][nf], 0, 0, 0);
        }
    }
    __syncthreads();
  }
  const int cb = bn + wc*WT;
#pragma unroll
  for (int mf = 0; mf < 4; ++mf){
    int row = bm + wr*64 + mf*16 + (lane >> 4)*4;
#pragma unroll
    for (int nf = 0; nf < NF; ++nf){
      int col = cb + nf*16 + (lane & 15);
#pragma unroll
      for (int r = 0; r < 4; ++r){
        float v = acc[mf][nf][r];
        if (BIAS) v += bias[col];
        if (ACT == 1) v = geluf(v);
        if (RESID) v += resid[(size_t)(row + r) * N + col];
        if (DUALOUT){
          float* op = (col < 384) ? Cm : C2;
          int oc = (col < 384) ? col : col - 384;
          op[(size_t)(row + r) * 384 + oc] = v;
        } else if (OSPLIT){
          u16* Gp = (u16*)Cm;
          u16 hi = f2bf(v);
          Gp[(size_t)(row + r) * (2*N) + col] = hi;
          Gp[(size_t)(row + r) * (2*N) + N + col] = f2bf(v - bf2f(hi));
        } else {
          Cm[(size_t)(row + r) * N + col] = v;
        }
      }
    }
  }
}

// ---------- depthwise conv 3x3 SAME + bias + silu ----------
__global__ __launch_bounds__(256) void conv_kernel(const float* __restrict__ xs, const float* __restrict__ cw,
                                                   const float* __restrict__ cb, float* __restrict__ u){
  int idx = blockIdx.x * 256 + threadIdx.x;
  if (idx >= ROWS * 96) return;
  int q = idx % 96; int l = idx / 96;
  int b = l / NL; int hw = l - b * NL; int h = hw / 56; int wc = hw - h * 56;
  int c4 = q * 4;
  float4 acc = *(const float4*)(cb + c4);
#pragma unroll
  for (int kh = 0; kh < 3; ++kh){
    int hh = h + kh - 1; if (hh < 0 || hh >= 56) continue;
#pragma unroll
    for (int kw = 0; kw < 3; ++kw){
      int wwc = wc + kw - 1; if (wwc < 0 || wwc >= 56) continue;
      float4 iv = *(const float4*)(xs + ((size_t)(b * NL + hh*56 + wwc)) * DIN + c4);
      float4 wv = *(const float4*)(cw + (size_t)(kh*3 + kw) * DIN + c4);
      acc.x += iv.x * wv.x; acc.y += iv.y * wv.y; acc.z += iv.z * wv.z; acc.w += iv.w * wv.w;
    }
  }
  float4 o; o.x = siluf(acc.x); o.y = siluf(acc.y); o.z = siluf(acc.z); o.w = siluf(acc.w);
  *(float4*)(u + (size_t)l * DIN + c4) = o;
}

// ---------- x_proj + dt_proj + softplus + w/feat (wave per row), BFS-pos output ----------
__global__ __launch_bounds__(256) void xdbl_kernel(const float* __restrict__ u,
    const float* __restrict__ xpw, const float* __restrict__ dtw_g,
    const float* __restrict__ dtb, const float* __restrict__ alog, const int* __restrict__ pos_g,
    float* __restrict__ wout, float* __restrict__ fout, float* __restrict__ csout){
  __shared__ float xw[14*384];
  __shared__ float dw[384*12];
  __shared__ float db[384];
  __shared__ float An[384];
  int t = threadIdx.x;
  for (int i = t; i < 14*384; i += 256) xw[i] = xpw[i];
  for (int i = t; i < 384*12; i += 256) dw[i] = dtw_g[i];
  for (int i = t; i < 384; i += 256){ db[i] = dtb[i]; An[i] = -expf(alog[i]); }
  __syncthreads();
  int wave = t >> 6, lane = t & 63;
  int row0 = blockIdx.x * 16 + wave * 4;
  for (int rr = 0; rr < 4; ++rr){
    int m = row0 + rr;
    int b = m / NL;
    int pos = pos_g[m];
    size_t orow = ((size_t)b * NL + pos) * DIN;
    const float* ur = u + (size_t)m * DIN;
    float u6[6];
#pragma unroll
    for (int j = 0; j < 6; ++j) u6[j] = ur[lane + 64*j];
    float xd[14];
#pragma unroll
    for (int r = 0; r < 14; ++r){
      float p = 0.f;
#pragma unroll
      for (int j = 0; j < 6; ++j) p += u6[j] * xw[r*384 + lane + 64*j];
      xd[r] = wredsum(p);
    }
    float Bs = xd[12], Cv = xd[13];
#pragma unroll
    for (int j = 0; j < 6; ++j){
      int dch = lane + 64*j;
      float pre = db[dch];
#pragma unroll
      for (int r = 0; r < 12; ++r) pre += xd[r] * dw[dch*12 + r];
      float dts = sofplus(pre);
      float wv = expf(dts * An[dch]);
      float fv = dts * Bs * u6[j];
      wout[orow + dch] = wv;
      fout[orow + dch] = fv;
    }
    if (lane == 0) csout[m] = Cv;
  }
}

// ---------- w transpose: [b][pos][384] -> planar [b][ch][pos] (64x64 LDS tiles) ----------
__global__ __launch_bounds__(256) void wtr_kernel(const float* __restrict__ in, float* __restrict__ out){
  __shared__ float tile[64][65];
  int blk = blockIdx.x;                  // 8 * 49 * 6
  int b = blk / (49*6);
  int r = blk - b*(49*6);
  int pt = r / 6, ct = r - pt*6;         // pos tile, channel tile
  int t = threadIdx.x;
  int tr = t >> 6, lane = t & 63;
  const float* src = in + ((size_t)b*NL + (size_t)pt*64) * DIN + ct*64;
#pragma unroll
  for (int k = 0; k < 16; ++k){
    int rr = tr + k*4;
    tile[rr][lane] = src[(size_t)rr*DIN + lane];
  }
  __syncthreads();
  float* dst = out + ((size_t)b*DIN + (size_t)ct*64) * NL + (size_t)pt*64;
#pragma unroll
  for (int k = 0; k < 16; ++k){
    int cc = tr + k*4;
    dst[(size_t)cc*NL + lane] = tile[lane][cc];
  }
}

// ---------- tree sweep v7: planar channel planes + PLANAR w stream (contiguous
// 256B window loads). One wave per channel, zero inter-wave barriers. ----------
__global__ __launch_bounds__(256) void sweep7_kernel(const float* __restrict__ featp, const float* __restrict__ wtr,
    float* __restrict__ Hp, const int* __restrict__ parpos_g,
    const int* __restrict__ lvl_g, const int* __restrict__ nlev_g){
  __shared__ float S[4*NL];    // 4 planar channel planes, 50176B -> 3 blocks/CU
  int blk = blockIdx.x;
  int b = blk & 7, q = blk >> 3;   // tree b pinned to XCD b
  int t = threadIdx.x, lane = t & 63, wv = t >> 6;
  int nl = nlev_g[b];
  const int* pg = parpos_g + b*NL;
  const int* lg = lvl_g + b*3200;
  const float* fbase = featp + (size_t)b*NL*DIN + q*4;
  const float* wbase = wtr + ((size_t)b*DIN + q*4 + wv) * NL;   // planar: this wave's channel row
  float*       hbase = Hp    + (size_t)b*NL*DIN + q*4;
  for (int i = t; i < NL; i += 256){
    float4 f = *(const float4*)(fbase + (size_t)i*DIN);
    S[0*NL + i] = f.x; S[1*NL + i] = f.y; S[2*NL + i] = f.z; S[3*NL + i] = f.w;
  }
  __syncthreads();
  float* Sp = &S[wv*NL];   // this wave's plane; no other wave touches it

  // ---- up-sweep: levels nl-1 .. 1, 64-wide windows, no barriers ----
  if (nl >= 2){
    int d  = nl - 1;
    int lo = lg[d], hi = lg[d+1];
    int nlo = (d >= 2) ? lg[d-1] : 0;
    float wc = 0.f; int ppc = 0;
    { int p = lo + lane; if (p < hi){ wc = wbase[p]; ppc = pg[p]; } }
    int base = lo;
    while (1){
      int d2 = d, nb = base + 64, nhi = hi, nlo2 = nlo, lo2 = lo;
      bool lvlchange = false;
      if (nb >= hi){
        d2 = d - 1; lvlchange = true;
        if (d2 >= 1){
          nb = nlo; nhi = lo; lo2 = nlo;
          nlo2 = (d2 >= 2) ? lg[d2-1] : 0;
        }
      }
      float wn = 0.f; int ppn = 0;
      if (d2 >= 1){ int pn = nb + lane; if (pn < nhi){ wn = wbase[pn]; ppn = pg[pn]; } }
      int p = base + lane;
      if (p < hi){
        float s = Sp[p];
        atomicAdd(&Sp[ppc], wc * s);
      }
      if (lvlchange){
        asm volatile("s_waitcnt lgkmcnt(0)" ::: "memory");   // intra-wave LDS ordering only
      }
      if (d2 < 1) break;
      d = d2; base = nb; hi = nhi; lo = lo2; nlo = nlo2; wc = wn; ppc = ppn;
    }
  }

  // ---- down-sweep: levels 1 .. nl-1 ----
  if (nl >= 2){
    int d = 1;
    int lo = lg[1], hi = lg[2];
    int hi2 = (nl >= 3) ? lg[3] : 0;
    float wc = 0.f; int ppc = 0;
    { int p = lo + lane; if (p < hi){ wc = wbase[p]; ppc = pg[p]; } }
    int base = lo;
    while (1){
      int d2 = d, nb = base + 64, nhi = hi, hi2n = hi2;
      bool lvlchange = false;
      if (nb >= hi){
        d2 = d + 1; lvlchange = true;
        nb = hi; nhi = hi2;
        hi2n = (d2 + 2 <= nl) ? lg[d2+2] : 0;
      }
      float wn = 0.f; int ppn = 0;
      if (d2 <= nl-1){ int pn = nb + lane; if (pn < nhi){ wn = wbase[pn]; ppn = pg[pn]; } }
      int p = base + lane;
      if (p < hi){
        float s = Sp[p]; float h = Sp[ppc];
        Sp[p] = s + wc * (h - wc * s);
      }
      if (lvlchange){
        asm volatile("s_waitcnt lgkmcnt(0)" ::: "memory");
      }
      if (d2 > nl-1) break;
      d = d2; base = nb; hi = nhi; hi2 = hi2n; wc = wn; ppc = ppn;
    }
  }

  __syncthreads();
  for (int i = t; i < NL; i += 256){
    float4 o;
    o.x = S[0*NL + i]; o.y = S[1*NL + i]; o.z = S[2*NL + i]; o.w = S[3*NL + i];
    *(float4*)(hbase + (size_t)i*DIN) = o;
  }
}

// ---------- y = Cs*H + Ds*u -> LN -> * silu(z) -> bf16 hi|lo pair (pos-row input) ----------
__global__ __launch_bounds__(256) void ynorm_kernel(const float* __restrict__ Hp, const float* __restrict__ u,
    const float* __restrict__ z, const float* __restrict__ Cs, const int* __restrict__ order_g,
    const float* __restrict__ Ds, const float* __restrict__ g, const float* __restrict__ bt,
    u16* __restrict__ out){
  int gw = (int)((blockIdx.x * 256u + threadIdx.x) >> 6);   // pos-row
  int lane = threadIdx.x & 63;
  if (gw >= ROWS) return;
  int b = gw / NL;
  int node = order_g[gw];
  size_t nrow = (size_t)b * NL + node;
  float Cv = Cs[nrow];
  const float* hr = Hp + (size_t)gw * DIN;
  const float* ur = u + nrow * DIN;
  const float* zr = z + nrow * DIN;
  float y[6]; float s = 0.f;
#pragma unroll
  for (int j = 0; j < 6; ++j){
    int dch = lane + 64*j;
    y[j] = Cv * hr[dch] + Ds[dch] * ur[dch];
    s += y[j];
  }
  s = wredsum(s);
  float mu = s * (1.0f / DIN);
  float q = 0.f;
#pragma unroll
  for (int j = 0; j < 6; ++j){ float dd = y[j] - mu; q += dd*dd; }
  q = wredsum(q);
  float rs = rsqrtf(q * (1.0f / DIN) + 1e-5f);
  u16* o = out + nrow * (2*DIN);
#pragma unroll
  for (int j = 0; j < 6; ++j){
    int dch = lane + 64*j;
    float yn = (y[j] - mu) * rs * g[dch] + bt[dch];
    float v = yn * siluf(zr[dch]);
    u16 hi = f2bf(v);
    o[dch] = hi; o[DIN + dch] = f2bf(v - bf2f(hi));
  }
}

// ---------- host orchestration ----------
extern "C" void kernel_launch(void* const* d_in, const int* in_sizes, int n_in,
                              void* d_out, int out_size, void* d_ws, size_t ws_size,
                              hipStream_t stream){
  const float* x_in       = (const float*)d_in[0];
  const float* norm1_w    = (const float*)d_in[1];
  const float* norm1_b    = (const float*)d_in[2];
  const float* in_proj_w  = (const float*)d_in[3];
  const float* conv_w     = (const float*)d_in[4];
  const float* conv_b     = (const float*)d_in[5];
  const float* x_proj_w   = (const float*)d_in[6];
  const float* dt_proj_w  = (const float*)d_in[7];
  const float* dt_proj_b  = (const float*)d_in[8];
  const float* A_log      = (const float*)d_in[9];
  const float* Ds         = (const float*)d_in[10];
  const float* out_norm_w = (const float*)d_in[11];
  const float* out_norm_b = (const float*)d_in[12];
  const float* out_proj_w = (const float*)d_in[13];
  const float* norm2_w    = (const float*)d_in[14];
  const float* norm2_b    = (const float*)d_in[15];
  const float* fc1_w      = (const float*)d_in[16];
  const float* fc1_b      = (const float*)d_in[17];
  const float* fc2_w      = (const float*)d_in[18];
  const float* fc2_b      = (const float*)d_in[19];
  const float* fnorm_w    = (const float*)d_in[20];
  const float* fnorm_b    = (const float*)d_in[21];

  float* ws = (float*)d_ws;
  float* X     = ws + 0;
  u16*   bufAh = (u16*)(ws + 4816896);
  float* bufZ  = ws + 9633792;
  float* bufW  = ws + 19267584;
  float* bufU  = ws + 28901376;
  float* bufF  = ws + 38535168;
  u16*   Gp    = (u16*)bufU;
  float* Csb   = ws + 48168960;
  int*   ordg  = (int*)(ws + 48194048);
  int*   ppg   = (int*)(ws + 48219136);
  int*   lvlg  = (int*)(ws + 48244224);
  int*   nlvg  = (int*)(ws + 48269824);
  u64*   keysg = (u64*)(ws + 48269832);
  float* nrm   = ws + 48368392;
  u16*   ipWp  = (u16*)(ws + 48393480);
  u16*   opWp  = (u16*)(ws + 48540936);
  u16*   fc1Wp = (u16*)(ws + 48614664);
  u16*   fc2Wp = (u16*)(ws + 48762120);
  int*   posg  = (int*)(ws + 48909576);
  float* wtrp  = ws + 48934664;          // planar w [b][384][NL], 9633792 f

  hipMemcpyAsync(X, x_in, (size_t)ROWS * NC * sizeof(float), hipMemcpyDeviceToDevice, stream);

  for (int i = 0; i < 2; ++i){
    wsplit_kernel<<<(768*192+255)/256, 256, 0, stream>>>(in_proj_w + (size_t)i*NHID*NC, ipWp, 768, 192);
    wsplit_kernel<<<(192*384+255)/256, 256, 0, stream>>>(out_proj_w + (size_t)i*NC*DIN, opWp, 192, 384);
    wsplit_kernel<<<(768*192+255)/256, 256, 0, stream>>>(fc1_w + (size_t)i*NHID*NC, fc1Wp, 768, 192);
    wsplit_kernel<<<(192*768+255)/256, 256, 0, stream>>>(fc2_w + (size_t)i*NC*NHID, fc2Wp, 192, 768);

    norms_kernel<<<ROWS/4, 256, 0, stream>>>(X, nrm);
    keys_kernel<<<(NB*NE)/4, 256, 0, stream>>>(X, nrm, keysg);
    tree_kernel<<<NB, 1024, 0, stream>>>(keysg, ordg, ppg, posg, lvlg, nlvg);

    ln_kernel<192,true><<<ROWS/4, 256, 0, stream>>>(X, norm1_w + i*NC, norm1_b + i*NC, bufAh);
    // fused in_proj: N=768, xs half -> bufF, z half -> bufZ
    mgemm_kernel<128,false,0,false,false,true><<<dim3(6,196), 256, 0, stream>>>(bufAh, ipWp, nullptr, nullptr, bufF, bufZ, ROWS, 768, 192);

    conv_kernel<<<(ROWS*96)/256, 256, 0, stream>>>(bufF, conv_w + (size_t)i*9*DIN, conv_b + i*DIN, bufU);

    // w/feat written in BFS-pos order (bufW = wperm, bufF = featperm)
    xdbl_kernel<<<ROWS/16, 256, 0, stream>>>(bufU, x_proj_w + (size_t)i*14*DIN, dt_proj_w + (size_t)i*DIN*12,
                                             dt_proj_b + i*DIN, A_log + i*DIN, posg, bufW, bufF, Csb);

    // transpose w to planar [b][ch][pos]
    wtr_kernel<<<8*49*6, 256, 0, stream>>>(bufW, wtrp);

    sweep7_kernel<<<NB*96, 256, 0, stream>>>(bufF, wtrp, bufF, ppg, lvlg, nlvg);

    ynorm_kernel<<<ROWS/4, 256, 0, stream>>>(bufF, bufU, bufZ, Csb, ordg, Ds + i*DIN,
                                             out_norm_w + i*DIN, out_norm_b + i*DIN, (u16*)bufW);

    mgemm_kernel<64,false,0,true,false,false><<<dim3(3,196), 256, 0, stream>>>((u16*)bufW, opWp, nullptr, X, X, nullptr, ROWS, 192, 384);

    ln_kernel<192,true><<<ROWS/4, 256, 0, stream>>>(X, norm2_w + i*NC, norm2_b + i*NC, bufAh);
    mgemm_kernel<128,true,1,false,true,false><<<dim3(6,196), 256, 0, stream>>>(bufAh, fc1Wp, fc1_b + i*NHID, nullptr, (float*)Gp, nullptr, ROWS, NHID, 192);
    mgemm_kernel<64,true,0,true,false,false><<<dim3(3,196), 256, 0, stream>>>(Gp, fc2Wp, fc2_b + i*NC, X, X, nullptr, ROWS, 192, 768);
  }

  ln_kernel<192,false><<<ROWS/4, 256, 0, stream>>>(X, fnorm_w, fnorm_b, d_out);
}

// Round 13
// 1568.454 us; speedup vs baseline: 1.1142x; 1.0726x over previous
//
#include <hip/hip_runtime.h>
#include <math.h>

#define NB 8
#define NC 192
#define DIN 384
#define NL 3136
#define ROWS (NB*NL)     // 25088
#define NE 6160
#define NHID 768

typedef unsigned short u16;
typedef unsigned int u32;
typedef unsigned long long u64;
typedef __attribute__((ext_vector_type(8))) short bh8;
typedef __attribute__((ext_vector_type(4))) float f4;

// global_load_lds width=16: wave-uniform LDS base + lane*16; per-lane global src.
typedef __attribute__((address_space(1))) const void gl_as1;
typedef __attribute__((address_space(3))) void gl_as3;
#define GL16(g, l) __builtin_amdgcn_global_load_lds((gl_as1*)(const void*)(g), (gl_as3*)(void*)(l), 16, 0, 0)

// ---------- helpers ----------
__device__ __forceinline__ float wredsum(float v){
  v += __shfl_xor(v, 1, 64); v += __shfl_xor(v, 2, 64); v += __shfl_xor(v, 4, 64);
  v += __shfl_xor(v, 8, 64); v += __shfl_xor(v, 16, 64); v += __shfl_xor(v, 32, 64);
  return v;
}
__device__ __forceinline__ void edge_decode(int e, int& u, int& v){
  if (e < 3080){ int h = e/55, w = e - h*55; u = h*56 + w; v = u + 1; }
  else { int e2 = e - 3080; int h = e2/56, w = e2 - h*56; u = h*56 + w; v = u + 56; }
}
__device__ __forceinline__ float siluf(float x){ return x / (1.0f + expf(-x)); }
__device__ __forceinline__ float sofplus(float x){ return fmaxf(x, 0.0f) + log1pf(expf(-fabsf(x))); }
__device__ __forceinline__ float geluf(float x){ return 0.5f * x * (1.0f + erff(x * 0.70710678118654752f)); }
__device__ __forceinline__ u16 f2bf(float x){
  u32 u = __float_as_uint(x);
  u32 r = (u + 0x7fffu + ((u >> 16) & 1u)) >> 16;
  return (u16)r;
}
__device__ __forceinline__ float bf2f(u16 h){ return __uint_as_float(((u32)h) << 16); }

// ---------- node norms (wave per node) ----------
__global__ __launch_bounds__(256) void norms_kernel(const float* __restrict__ x, float* __restrict__ nrm){
  int gw = (int)((blockIdx.x * 256u + threadIdx.x) >> 6);
  int lane = threadIdx.x & 63;
  if (gw >= ROWS) return;
  const float* r = x + (size_t)gw * NC;
  float s = 0.f;
#pragma unroll
  for (int j = 0; j < 3; ++j){ float v = r[lane + 64*j]; s += v*v; }
  s = wredsum(s);
  if (lane == 0) nrm[gw] = sqrtf(s) + 1e-8f;
}

// ---------- edge keys (wave per edge) ----------
__global__ __launch_bounds__(256) void keys_kernel(const float* __restrict__ x, const float* __restrict__ nrm,
                                                   u64* __restrict__ keys){
  int gw = (int)((blockIdx.x * 256u + threadIdx.x) >> 6);
  int lane = threadIdx.x & 63;
  if (gw >= NB * NE) return;
  int b = gw / NE, e = gw - b * NE;
  int u, v; edge_decode(e, u, v);
  const float* ru = x + ((size_t)b * NL + u) * NC;
  const float* rv = x + ((size_t)b * NL + v) * NC;
  float s = 0.f;
#pragma unroll
  for (int j = 0; j < 3; ++j){ s += ru[lane + 64*j] * rv[lane + 64*j]; }
  s = wredsum(s);
  if (lane == 0){
    float cosv = s / (nrm[b*NL + u] * nrm[b*NL + v]);
    float wgt = expf(1.0f - cosv);
    keys[(size_t)b*NE + e] = ((u64)__float_as_uint(wgt) << 32) | (u64)(u32)e;
  }
}

// ---------- per-image: Boruvka MST (batched) + adjl4 + posOf-free single-wave BFS ----------
__global__ __launch_bounds__(1024) void tree_kernel(const u64* __restrict__ keys_g,
      int* __restrict__ order_g, int* __restrict__ parpos_g, int* __restrict__ pos_g,
      int* __restrict__ lvl_g, int* __restrict__ nlev_g){
  __shared__ __align__(16) char sm[62736];
  const int b = blockIdx.x;
  const int t = threadIdx.x;
  const int NT = 1024;
  u64* best   = (u64*)sm;            // [3136] @0     (25088)
  u16* parent = (u16*)(sm + 25088);  // [3136] (6272)
  u16* comp   = (u16*)(sm + 31360);  // [3136] (6272)
  u16* mstU   = (u16*)(sm + 37632);  // [3136] (6272)
  u16* mstV   = (u16*)(sm + 43904);  // [3136] (6272)
  u32* cnts   = (u32*)(sm + 56448);  // [4]
  u16* adjl4  = (u16*)sm;            // [3136*4] @0 (over best)
  u32* deg    = (u32*)(sm + 25088);  // [3136] (over parent+comp)
  u32* fr     = (u32*)(sm + 37632);  // [3136] (over mstU+mstV): node | pnode<<16
  u16* ppos   = (u16*)(sm + 50176);  // [3136]

  const u64* kb = keys_g + (size_t)b * NE;
  for (int v = t; v < NL; v += NT) parent[v] = (u16)v;
  if (t == 0){ cnts[0] = 0; cnts[3] = 0xffffffffu; }
  __syncthreads();

  u32 gpass = 0;
  for (int round = 0; round < 24; ++round){
    for (int it = 0; it < 12; ++it){
      int vv[4]; u16 pv[4]; int nb2 = 0;
#pragma unroll
      for (int j = 0; j < 4; ++j){ int v = t + j*NT; if (v < NL){ vv[nb2] = v; pv[nb2] = parent[v]; ++nb2; } }
      u16 gp[4];
      for (int j = 0; j < nb2; ++j) gp[j] = parent[pv[j]];
      bool ch = false;
      for (int j = 0; j < nb2; ++j){ if (gp[j] != pv[j]){ parent[vv[j]] = gp[j]; ch = true; } }
      bool docheck = (it & 1);
      if (docheck && ch) cnts[3] = gpass;
      __syncthreads();
      if (docheck){
        u32 seen = cnts[3];
        __syncthreads();
        u32 cur = gpass; ++gpass;
        if (seen != cur) break;
      }
    }
    for (int v = t; v < NL; v += NT){ comp[v] = parent[v]; best[v] = ~0ull; }
    if (t == 0) cnts[2] = 0;
    __syncthreads();
    {
      int ee[7]; int eu[7], ev[7]; u16 cu[7], cv[7]; u64 kk[7]; int nb2 = 0;
#pragma unroll
      for (int j = 0; j < 7; ++j){
        int e = t + j*NT;
        if (e < NE){ ee[nb2] = e; int u, v; edge_decode(e, u, v); eu[nb2] = u; ev[nb2] = v; ++nb2; }
      }
      for (int j = 0; j < nb2; ++j){ cu[j] = comp[eu[j]]; cv[j] = comp[ev[j]]; }
      for (int j = 0; j < nb2; ++j){ kk[j] = kb[ee[j]]; }
      for (int j = 0; j < nb2; ++j){
        if (cu[j] != cv[j]){
          atomicMin(&best[cu[j]], kk[j]);
          atomicMin(&best[cv[j]], kk[j]);
        }
      }
    }
    __syncthreads();
    {
      int rr[4]; u64 bk[4]; int nb2 = 0;
#pragma unroll
      for (int j = 0; j < 4; ++j){ int r = t + j*NT; if (r < NL){ rr[nb2] = r; ++nb2; } }
      u16 cr[4];
      for (int j = 0; j < nb2; ++j) cr[j] = comp[rr[j]];
      for (int j = 0; j < nb2; ++j) bk[j] = (cr[j] == (u16)rr[j]) ? best[rr[j]] : ~0ull;
      int uu[4], vv2[4]; u16 ru2[4], rv2[4];
      for (int j = 0; j < nb2; ++j){
        if (bk[j] != ~0ull){ int e = (int)(u32)bk[j]; edge_decode(e, uu[j], vv2[j]); }
      }
      for (int j = 0; j < nb2; ++j){
        if (bk[j] != ~0ull){ ru2[j] = comp[uu[j]]; rv2[j] = comp[vv2[j]]; }
      }
      for (int j = 0; j < nb2; ++j){
        if (bk[j] != ~0ull){
          int r = rr[j];
          u16 other = (ru2[j] == (u16)r) ? rv2[j] : ru2[j];
          bool mutual = (best[other] == bk[j]);
          if (!mutual || (u16)r < other){
            parent[r] = other;
            u32 id = atomicAdd(&cnts[0], 1);
            mstU[id] = (u16)uu[j]; mstV[id] = (u16)vv2[j];
            cnts[2] = 1;
          }
        }
      }
    }
    __syncthreads();
    if (cnts[0] >= (u32)(NL - 1) || cnts[2] == 0) break;
  }
  __syncthreads();

  const int nm = NL - 1;
  for (int v = t; v < NL; v += NT){
    deg[v] = 0;
    *(u64*)&adjl4[v*4] = 0xffffffffffffffffull;
  }
  __syncthreads();
  {
    int uu[4], vv2[4]; int nb2 = 0;
#pragma unroll
    for (int j = 0; j < 4; ++j){
      int i = t + j*NT;
      if (i < nm){ uu[nb2] = mstU[i]; vv2[nb2] = mstV[i]; ++nb2; }
    }
    for (int j = 0; j < nb2; ++j){
      u32 s1 = atomicAdd(&deg[uu[j]], 1); adjl4[uu[j]*4 + s1] = (u16)vv2[j];
      u32 s2 = atomicAdd(&deg[vv2[j]], 1); adjl4[vv2[j]*4 + s2] = (u16)uu[j];
    }
  }
  __syncthreads();

  if (t == 0){
    fr[0] = 0u | (0xffffu << 16);
    ppos[0] = 0;
    cnts[1] = 1;
    lvl_g[b*3200 + 0] = 0; lvl_g[b*3200 + 1] = 1;
  }
  __syncthreads();
  if (t < 64){
    int flo = 0, fhi = 1, d = 1;
    while (fhi < NL){
      for (int base2 = flo; base2 < fhi; base2 += 64){
        int idx = base2 + t;
        if (idx < fhi){
          u32 f = fr[idx];
          int u = (int)(f & 0xffffu), pn = (int)(f >> 16);
          u64 four = *(const u64*)&adjl4[u*4];
#pragma unroll
          for (int j = 0; j < 4; ++j){
            int v = (int)((four >> (16*j)) & 0xffffu);
            if (v != 0xffff && v != pn){
              u32 pos = atomicAdd(&cnts[1], 1);
              fr[pos] = (u32)v | ((u32)u << 16);
              ppos[pos] = (u16)idx;
            }
          }
        }
        asm volatile("s_waitcnt lgkmcnt(0)" ::: "memory");
      }
      int nf = (int)cnts[1];
      if (t == 0) lvl_g[b*3200 + d + 1] = nf;
      flo = fhi; fhi = nf; ++d;
      if (nf == flo) break;
    }
    if (t == 0) nlev_g[b] = d;
  }
  __syncthreads();

  for (int p = t; p < NL; p += NT){
    u32 f = fr[p];
    int node = (int)(f & 0xffffu);
    order_g[b*NL + p] = node;
    parpos_g[b*NL + p] = (int)ppos[p];
    pos_g[b*NL + node] = p;
  }
}

// ---------- layernorm (wave per row); BF16OUT -> plain bf16 row ----------
template<int D, bool BF16OUT>
__global__ __launch_bounds__(256) void ln_kernel(const float* __restrict__ in, const float* __restrict__ g,
                                                 const float* __restrict__ bt, void* __restrict__ outv){
  int gw = (int)((blockIdx.x * 256u + threadIdx.x) >> 6);
  int lane = threadIdx.x & 63;
  if (gw >= ROWS) return;
  constexpr int J = D / 64;
  const float* r = in + (size_t)gw * D;
  float v[J]; float s = 0.f;
#pragma unroll
  for (int j = 0; j < J; ++j){ v[j] = r[lane + 64*j]; s += v[j]; }
  s = wredsum(s);
  float mu = s * (1.0f / D);
  float q = 0.f;
#pragma unroll
  for (int j = 0; j < J; ++j){ float dd = v[j] - mu; q += dd*dd; }
  q = wredsum(q);
  float rs = rsqrtf(q * (1.0f / D) + 1e-5f);
  if (BF16OUT){
    u16* o = (u16*)outv + (size_t)gw * D;
#pragma unroll
    for (int j = 0; j < J; ++j){
      int dch = lane + 64*j;
      float y = (v[j] - mu) * rs * g[dch] + bt[dch];
      o[dch] = f2bf(y);
    }
  } else {
    float* o = (float*)outv + (size_t)gw * D;
#pragma unroll
    for (int j = 0; j < J; ++j){ int dch = lane + 64*j; o[dch] = (v[j] - mu) * rs * g[dch] + bt[dch]; }
  }
}

// ---------- weight split fp32 [N,K] -> bf16 [N, hi(K)|lo(K)] ----------
__global__ __launch_bounds__(256) void wsplit_kernel(const float* __restrict__ W, u16* __restrict__ o, int N, int K){
  int i = blockIdx.x * 256 + threadIdx.x;
  if (i >= N * K) return;
  int r = i / K, c = i - r * K;
  float v = W[i];
  u16 hi = f2bf(v);
  o[(size_t)r * 2 * K + c] = hi;
  o[(size_t)r * 2 * K + K + c] = f2bf(v - bf2f(hi));
}

// ---------- MFMA GEMM: A plain bf16 [M,K]; W split hi|lo [N,2K].
// C = A*(Wh+Wl)^T (2 MFMA/frag). global_load_lds staging, pre-swizzled src.
// DUALOUT: N=768 -> cols<384 to Cm, cols>=384 to C2 (both fp32 stride 384).
// OBF16: write bf16 to (u16*)Cm. ----------
template<int BN, bool BIAS, int ACT, bool RESID, bool OBF16, bool DUALOUT>
__global__ __launch_bounds__(256) void mgemm_kernel(
    const u16* __restrict__ Ap, const u16* __restrict__ Wp,
    const float* __restrict__ bias, const float* __restrict__ resid,
    float* __restrict__ Cm, float* __restrict__ C2, int M, int N, int K){
  static_assert(BN == 64 || BN == 128, "BN");
  constexpr int WT = (BN == 128) ? 64 : 32;
  constexpr int NF = WT / 16;
  __shared__ short Ah[128*64];
  __shared__ short Wh[BN*64], Wl[BN*64];
  const int bm = blockIdx.y * 128, bn = blockIdx.x * BN;
  const int tid = threadIdx.x, lane = tid & 63, wid = tid >> 6;
  const int wr = wid >> 1, wc = wid & 1;
  const int K2 = 2 * K;
  f4 acc[4][NF];
#pragma unroll
  for (int mf = 0; mf < 4; ++mf)
#pragma unroll
    for (int nf = 0; nf < NF; ++nf) acc[mf][nf] = (f4){0.f,0.f,0.f,0.f};

  for (int k0 = 0; k0 < K; k0 += 64){
    // A tile: 128x64 bf16 (plain [M,K] layout)
#pragma unroll
    for (int j = 0; j < 4; ++j){
      int isb = wid*4 + j;
      int r = isb*8 + (lane >> 3);
      int c = lane & 7;
      const u16* src = Ap + (size_t)(bm + r) * K + k0 + ((c ^ (r & 7)) << 3);
      GL16(src, &Ah[isb*512]);
    }
    // W tiles: hi + lo ([N,2K] layout)
#pragma unroll
    for (int j = 0; j < BN/32; ++j){
      int isb = wid*(BN/32) + j;
      int r = isb*8 + (lane >> 3);
      int c = lane & 7;
      const u16* src = Wp + (size_t)(bn + r) * K2 + k0 + ((c ^ (r & 7)) << 3);
      GL16(src,     &Wh[isb*512]);
      GL16(src + K, &Wl[isb*512]);
    }
    __syncthreads();
#pragma unroll
    for (int kk = 0; kk < 2; ++kk){
      bh8 whf[NF], wlf[NF], ahf[4];
#pragma unroll
      for (int nf = 0; nf < NF; ++nf){
        int rw = wc*WT + nf*16 + (lane & 15);
        int c = kk*4 + (lane >> 4);
        int ad = rw*64 + ((c ^ (rw & 7)) * 8);
        whf[nf] = *(const bh8*)&Wh[ad];
        wlf[nf] = *(const bh8*)&Wl[ad];
      }
#pragma unroll
      for (int mf = 0; mf < 4; ++mf){
        int ra = wr*64 + mf*16 + (lane & 15);
        int c = kk*4 + (lane >> 4);
        int ad = ra*64 + ((c ^ (ra & 7)) * 8);
        ahf[mf] = *(const bh8*)&Ah[ad];
      }
#pragma unroll
      for (int mf = 0; mf < 4; ++mf)
#pragma unroll
        for (int nf = 0; nf < NF; ++nf){
          acc[mf][nf] = __builtin_amdgcn_mfma_f32_16x16x32_bf16(ahf[mf], whf[nf], acc[mf][nf], 0, 0, 0);
          acc[mf][nf] = __builtin_amdgcn_mfma_f32_16x16x32_bf16(ahf[mf], wlf[nf], acc[mf][nf], 0, 0, 0);
        }
    }
    __syncthreads();
  }
  const int cb = bn + wc*WT;
#pragma unroll
  for (int mf = 0; mf < 4; ++mf){
    int row = bm + wr*64 + mf*16 + (lane >> 4)*4;
#pragma unroll
    for (int nf = 0; nf < NF; ++nf){
      int col = cb + nf*16 + (lane & 15);
#pragma unroll
      for (int r = 0; r < 4; ++r){
        float v = acc[mf][nf][r];
        if (BIAS) v += bias[col];
        if (ACT == 1) v = geluf(v);
        if (RESID) v += resid[(size_t)(row + r) * N + col];
        if (DUALOUT){
          float* op = (col < 384) ? Cm : C2;
          int oc = (col < 384) ? col : col - 384;
          op[(size_t)(row + r) * 384 + oc] = v;
        } else if (OBF16){
          u16* op = (u16*)Cm;
          op[(size_t)(row + r) * N + col] = f2bf(v);
        } else {
          Cm[(size_t)(row + r) * N + col] = v;
        }
      }
    }
  }
}

// ---------- depthwise conv 3x3 SAME + bias + silu ----------
__global__ __launch_bounds__(256) void conv_kernel(const float* __restrict__ xs, const float* __restrict__ cw,
                                                   const float* __restrict__ cb, float* __restrict__ u){
  int idx = blockIdx.x * 256 + threadIdx.x;
  if (idx >= ROWS * 96) return;
  int q = idx % 96; int l = idx / 96;
  int b = l / NL; int hw = l - b * NL; int h = hw / 56; int wc = hw - h * 56;
  int c4 = q * 4;
  float4 acc = *(const float4*)(cb + c4);
#pragma unroll
  for (int kh = 0; kh < 3; ++kh){
    int hh = h + kh - 1; if (hh < 0 || hh >= 56) continue;
#pragma unroll
    for (int kw = 0; kw < 3; ++kw){
      int wwc = wc + kw - 1; if (wwc < 0 || wwc >= 56) continue;
      float4 iv = *(const float4*)(xs + ((size_t)(b * NL + hh*56 + wwc)) * DIN + c4);
      float4 wv = *(const float4*)(cw + (size_t)(kh*3 + kw) * DIN + c4);
      acc.x += iv.x * wv.x; acc.y += iv.y * wv.y; acc.z += iv.z * wv.z; acc.w += iv.w * wv.w;
    }
  }
  float4 o; o.x = siluf(acc.x); o.y = siluf(acc.y); o.z = siluf(acc.z); o.w = siluf(acc.w);
  *(float4*)(u + (size_t)l * DIN + c4) = o;
}

// ---------- x_proj + dt_proj + softplus + w/feat (wave per row), BFS-pos output ----------
__global__ __launch_bounds__(256) void xdbl_kernel(const float* __restrict__ u,
    const float* __restrict__ xpw, const float* __restrict__ dtw_g,
    const float* __restrict__ dtb, const float* __restrict__ alog, const int* __restrict__ pos_g,
    float* __restrict__ wout, float* __restrict__ fout, float* __restrict__ csout){
  __shared__ float xw[14*384];
  __shared__ float dw[384*12];
  __shared__ float db[384];
  __shared__ float An[384];
  int t = threadIdx.x;
  for (int i = t; i < 14*384; i += 256) xw[i] = xpw[i];
  for (int i = t; i < 384*12; i += 256) dw[i] = dtw_g[i];
  for (int i = t; i < 384; i += 256){ db[i] = dtb[i]; An[i] = -expf(alog[i]); }
  __syncthreads();
  int wave = t >> 6, lane = t & 63;
  int row0 = blockIdx.x * 16 + wave * 4;
  for (int rr = 0; rr < 4; ++rr){
    int m = row0 + rr;
    int b = m / NL;
    int pos = pos_g[m];
    size_t orow = ((size_t)b * NL + pos) * DIN;
    const float* ur = u + (size_t)m * DIN;
    float u6[6];
#pragma unroll
    for (int j = 0; j < 6; ++j) u6[j] = ur[lane + 64*j];
    float xd[14];
#pragma unroll
    for (int r = 0; r < 14; ++r){
      float p = 0.f;
#pragma unroll
      for (int j = 0; j < 6; ++j) p += u6[j] * xw[r*384 + lane + 64*j];
      xd[r] = wredsum(p);
    }
    float Bs = xd[12], Cv = xd[13];
#pragma unroll
    for (int j = 0; j < 6; ++j){
      int dch = lane + 64*j;
      float pre = db[dch];
#pragma unroll
      for (int r = 0; r < 12; ++r) pre += xd[r] * dw[dch*12 + r];
      float dts = sofplus(pre);
      float wv = expf(dts * An[dch]);
      float fv = dts * Bs * u6[j];
      wout[orow + dch] = wv;
      fout[orow + dch] = fv;
    }
    if (lane == 0) csout[m] = Cv;
  }
}

// ---------- w transpose: [b][pos][384] -> planar [b][ch][pos] (64x64 LDS tiles) ----------
__global__ __launch_bounds__(256) void wtr_kernel(const float* __restrict__ in, float* __restrict__ out){
  __shared__ float tile[64][65];
  int blk = blockIdx.x;                  // 8 * 49 * 6
  int b = blk / (49*6);
  int r = blk - b*(49*6);
  int pt = r / 6, ct = r - pt*6;
  int t = threadIdx.x;
  int tr = t >> 6, lane = t & 63;
  const float* src = in + ((size_t)b*NL + (size_t)pt*64) * DIN + ct*64;
#pragma unroll
  for (int k = 0; k < 16; ++k){
    int rr = tr + k*4;
    tile[rr][lane] = src[(size_t)rr*DIN + lane];
  }
  __syncthreads();
  float* dst = out + ((size_t)b*DIN + (size_t)ct*64) * NL + (size_t)pt*64;
#pragma unroll
  for (int k = 0; k < 16; ++k){
    int cc = tr + k*4;
    dst[(size_t)cc*NL + lane] = tile[lane][cc];
  }
}

// ---------- tree sweep v7 (unchanged) ----------
__global__ __launch_bounds__(256) void sweep7_kernel(const float* __restrict__ featp, const float* __restrict__ wtr,
    float* __restrict__ Hp, const int* __restrict__ parpos_g,
    const int* __restrict__ lvl_g, const int* __restrict__ nlev_g){
  __shared__ float S[4*NL];
  int blk = blockIdx.x;
  int b = blk & 7, q = blk >> 3;
  int t = threadIdx.x, lane = t & 63, wv = t >> 6;
  int nl = nlev_g[b];
  const int* pg = parpos_g + b*NL;
  const int* lg = lvl_g + b*3200;
  const float* fbase = featp + (size_t)b*NL*DIN + q*4;
  const float* wbase = wtr + ((size_t)b*DIN + q*4 + wv) * NL;
  float*       hbase = Hp    + (size_t)b*NL*DIN + q*4;
  for (int i = t; i < NL; i += 256){
    float4 f = *(const float4*)(fbase + (size_t)i*DIN);
    S[0*NL + i] = f.x; S[1*NL + i] = f.y; S[2*NL + i] = f.z; S[3*NL + i] = f.w;
  }
  __syncthreads();
  float* Sp = &S[wv*NL];

  if (nl >= 2){
    int d  = nl - 1;
    int lo = lg[d], hi = lg[d+1];
    int nlo = (d >= 2) ? lg[d-1] : 0;
    float wc = 0.f; int ppc = 0;
    { int p = lo + lane; if (p < hi){ wc = wbase[p]; ppc = pg[p]; } }
    int base = lo;
    while (1){
      int d2 = d, nb = base + 64, nhi = hi, nlo2 = nlo, lo2 = lo;
      bool lvlchange = false;
      if (nb >= hi){
        d2 = d - 1; lvlchange = true;
        if (d2 >= 1){
          nb = nlo; nhi = lo; lo2 = nlo;
          nlo2 = (d2 >= 2) ? lg[d2-1] : 0;
        }
      }
      float wn = 0.f; int ppn = 0;
      if (d2 >= 1){ int pn = nb + lane; if (pn < nhi){ wn = wbase[pn]; ppn = pg[pn]; } }
      int p = base + lane;
      if (p < hi){
        float s = Sp[p];
        atomicAdd(&Sp[ppc], wc * s);
      }
      if (lvlchange){
        asm volatile("s_waitcnt lgkmcnt(0)" ::: "memory");
      }
      if (d2 < 1) break;
      d = d2; base = nb; hi = nhi; lo = lo2; nlo = nlo2; wc = wn; ppc = ppn;
    }
  }

  if (nl >= 2){
    int d = 1;
    int lo = lg[1], hi = lg[2];
    int hi2 = (nl >= 3) ? lg[3] : 0;
    float wc = 0.f; int ppc = 0;
    { int p = lo + lane; if (p < hi){ wc = wbase[p]; ppc = pg[p]; } }
    int base = lo;
    while (1){
      int d2 = d, nb = base + 64, nhi = hi, hi2n = hi2;
      bool lvlchange = false;
      if (nb >= hi){
        d2 = d + 1; lvlchange = true;
        nb = hi; nhi = hi2;
        hi2n = (d2 + 2 <= nl) ? lg[d2+2] : 0;
      }
      float wn = 0.f; int ppn = 0;
      if (d2 <= nl-1){ int pn = nb + lane; if (pn < nhi){ wn = wbase[pn]; ppn = pg[pn]; } }
      int p = base + lane;
      if (p < hi){
        float s = Sp[p]; float h = Sp[ppc];
        Sp[p] = s + wc * (h - wc * s);
      }
      if (lvlchange){
        asm volatile("s_waitcnt lgkmcnt(0)" ::: "memory");
      }
      if (d2 > nl-1) break;
      d = d2; base = nb; hi = nhi; hi2 = hi2n; wc = wn; ppc = ppn;
    }
  }

  __syncthreads();
  for (int i = t; i < NL; i += 256){
    float4 o;
    o.x = S[0*NL + i]; o.y = S[1*NL + i]; o.z = S[2*NL + i]; o.w = S[3*NL + i];
    *(float4*)(hbase + (size_t)i*DIN) = o;
  }
}

// ---------- y = Cs*H + Ds*u -> LN -> * silu(z) -> plain bf16 (pos-row input) ----------
__global__ __launch_bounds__(256) void ynorm_kernel(const float* __restrict__ Hp, const float* __restrict__ u,
    const float* __restrict__ z, const float* __restrict__ Cs, const int* __restrict__ order_g,
    const float* __restrict__ Ds, const float* __restrict__ g, const float* __restrict__ bt,
    u16* __restrict__ out){
  int gw = (int)((blockIdx.x * 256u + threadIdx.x) >> 6);   // pos-row
  int lane = threadIdx.x & 63;
  if (gw >= ROWS) return;
  int b = gw / NL;
  int node = order_g[gw];
  size_t nrow = (size_t)b * NL + node;
  float Cv = Cs[nrow];
  const float* hr = Hp + (size_t)gw * DIN;
  const float* ur = u + nrow * DIN;
  const float* zr = z + nrow * DIN;
  float y[6]; float s = 0.f;
#pragma unroll
  for (int j = 0; j < 6; ++j){
    int dch = lane + 64*j;
    y[j] = Cv * hr[dch] + Ds[dch] * ur[dch];
    s += y[j];
  }
  s = wredsum(s);
  float mu = s * (1.0f / DIN);
  float q = 0.f;
#pragma unroll
  for (int j = 0; j < 6; ++j){ float dd = y[j] - mu; q += dd*dd; }
  q = wredsum(q);
  float rs = rsqrtf(q * (1.0f / DIN) + 1e-5f);
  u16* o = out + nrow * DIN;
#pragma unroll
  for (int j = 0; j < 6; ++j){
    int dch = lane + 64*j;
    float yn = (y[j] - mu) * rs * g[dch] + bt[dch];
    float v = yn * siluf(zr[dch]);
    o[dch] = f2bf(v);
  }
}

// ---------- host orchestration ----------
extern "C" void kernel_launch(void* const* d_in, const int* in_sizes, int n_in,
                              void* d_out, int out_size, void* d_ws, size_t ws_size,
                              hipStream_t stream){
  const float* x_in       = (const float*)d_in[0];
  const float* norm1_w    = (const float*)d_in[1];
  const float* norm1_b    = (const float*)d_in[2];
  const float* in_proj_w  = (const float*)d_in[3];
  const float* conv_w     = (const float*)d_in[4];
  const float* conv_b     = (const float*)d_in[5];
  const float* x_proj_w   = (const float*)d_in[6];
  const float* dt_proj_w  = (const float*)d_in[7];
  const float* dt_proj_b  = (const float*)d_in[8];
  const float* A_log      = (const float*)d_in[9];
  const float* Ds         = (const float*)d_in[10];
  const float* out_norm_w = (const float*)d_in[11];
  const float* out_norm_b = (const float*)d_in[12];
  const float* out_proj_w = (const float*)d_in[13];
  const float* norm2_w    = (const float*)d_in[14];
  const float* norm2_b    = (const float*)d_in[15];
  const float* fc1_w      = (const float*)d_in[16];
  const float* fc1_b      = (const float*)d_in[17];
  const float* fc2_w      = (const float*)d_in[18];
  const float* fc2_b      = (const float*)d_in[19];
  const float* fnorm_w    = (const float*)d_in[20];
  const float* fnorm_b    = (const float*)d_in[21];

  float* ws = (float*)d_ws;
  float* X     = ws + 0;
  u16*   bufAh = (u16*)(ws + 4816896);   // [M,192] bf16
  float* bufZ  = ws + 9633792;
  float* bufW  = ws + 19267584;          // w fp32 / ynorm-out bf16 [M,384]
  float* bufU  = ws + 28901376;
  float* bufF  = ws + 38535168;
  u16*   Gp    = (u16*)bufU;             // fc1 out bf16 [M,768] (aliases bufU after its last use? no - bufU holds u, used by ynorm before fc1. Gp written after ynorm read of u? fc1 runs after out_proj; u no longer needed)
  float* Csb   = ws + 48168960;
  int*   ordg  = (int*)(ws + 48194048);
  int*   ppg   = (int*)(ws + 48219136);
  int*   lvlg  = (int*)(ws + 48244224);
  int*   nlvg  = (int*)(ws + 48269824);
  u64*   keysg = (u64*)(ws + 48269832);
  float* nrm   = ws + 48368392;
  u16*   ipWp  = (u16*)(ws + 48393480);
  u16*   opWp  = (u16*)(ws + 48540936);
  u16*   fc1Wp = (u16*)(ws + 48614664);
  u16*   fc2Wp = (u16*)(ws + 48762120);
  int*   posg  = (int*)(ws + 48909576);
  float* wtrp  = ws + 48934664;

  hipMemcpyAsync(X, x_in, (size_t)ROWS * NC * sizeof(float), hipMemcpyDeviceToDevice, stream);

  for (int i = 0; i < 2; ++i){
    wsplit_kernel<<<(768*192+255)/256, 256, 0, stream>>>(in_proj_w + (size_t)i*NHID*NC, ipWp, 768, 192);
    wsplit_kernel<<<(192*384+255)/256, 256, 0, stream>>>(out_proj_w + (size_t)i*NC*DIN, opWp, 192, 384);
    wsplit_kernel<<<(768*192+255)/256, 256, 0, stream>>>(fc1_w + (size_t)i*NHID*NC, fc1Wp, 768, 192);
    wsplit_kernel<<<(192*768+255)/256, 256, 0, stream>>>(fc2_w + (size_t)i*NC*NHID, fc2Wp, 192, 768);

    norms_kernel<<<ROWS/4, 256, 0, stream>>>(X, nrm);
    keys_kernel<<<(NB*NE)/4, 256, 0, stream>>>(X, nrm, keysg);
    tree_kernel<<<NB, 1024, 0, stream>>>(keysg, ordg, ppg, posg, lvlg, nlvg);

    ln_kernel<192,true><<<ROWS/4, 256, 0, stream>>>(X, norm1_w + i*NC, norm1_b + i*NC, bufAh);
    // fused in_proj: N=768, xs half -> bufF (fp32), z half -> bufZ (fp32)
    mgemm_kernel<128,false,0,false,false,true><<<dim3(6,196), 256, 0, stream>>>(bufAh, ipWp, nullptr, nullptr, bufF, bufZ, ROWS, 768, 192);

    conv_kernel<<<(ROWS*96)/256, 256, 0, stream>>>(bufF, conv_w + (size_t)i*9*DIN, conv_b + i*DIN, bufU);

    xdbl_kernel<<<ROWS/16, 256, 0, stream>>>(bufU, x_proj_w + (size_t)i*14*DIN, dt_proj_w + (size_t)i*DIN*12,
                                             dt_proj_b + i*DIN, A_log + i*DIN, posg, bufW, bufF, Csb);

    wtr_kernel<<<8*49*6, 256, 0, stream>>>(bufW, wtrp);

    sweep7_kernel<<<NB*96, 256, 0, stream>>>(bufF, wtrp, bufF, ppg, lvlg, nlvg);

    // ynorm -> plain bf16 [M,384] into bufW
    ynorm_kernel<<<ROWS/4, 256, 0, stream>>>(bufF, bufU, bufZ, Csb, ordg, Ds + i*DIN,
                                             out_norm_w + i*DIN, out_norm_b + i*DIN, (u16*)bufW);

    mgemm_kernel<64,false,0,true,false,false><<<dim3(3,196), 256, 0, stream>>>((u16*)bufW, opWp, nullptr, X, X, nullptr, ROWS, 192, 384);

    ln_kernel<192,true><<<ROWS/4, 256, 0, stream>>>(X, norm2_w + i*NC, norm2_b + i*NC, bufAh);
    // fc1 -> plain bf16 G [M,768]
    mgemm_kernel<128,true,1,false,true,false><<<dim3(6,196), 256, 0, stream>>>(bufAh, fc1Wp, fc1_b + i*NHID, nullptr, (float*)Gp, nullptr, ROWS, NHID, 192);
    mgemm_kernel<64,true,0,true,false,false><<<dim3(3,196), 256, 0, stream>>>(Gp, fc2Wp, fc2_b + i*NC, X, X, nullptr, ROWS, 192, 768);
  }

  ln_kernel<192,false><<<ROWS/4, 256, 0, stream>>>(X, fnorm_w, fnorm_b, d_out);
}